// Round 14
// baseline (204.362 us; speedup 1.0000x reference)
//
#include <hip/hip_runtime.h>

// Problem constants (B,T,C,H,Dh) = (4,2048,1024,16,64); M = B*T = 8192.
#define SEQ_T 2048
#define NBATCH 4
#define CDIM 1024
#define NHEAD 16
#define MROWS 8192      // NBATCH * SEQ_T
#define QKVC 3072       // 3*CDIM

typedef unsigned short u16;
typedef __bf16 bf16x8 __attribute__((ext_vector_type(8)));
typedef float f32x4 __attribute__((ext_vector_type(4)));
typedef unsigned short u16x8 __attribute__((ext_vector_type(8)));
typedef unsigned uint32x4 __attribute__((ext_vector_type(4)));

__device__ __forceinline__ u16 f32_to_bf16(float f) {
  union { float f; unsigned int u; } v; v.f = f;
  unsigned int u = v.u;
  unsigned int r = ((u >> 16) & 1u) + 0x7fffu;   // round-to-nearest-even
  return (u16)((u + r) >> 16);
}

__device__ __forceinline__ void gload_lds16(const u16* g, u16* l) {
  __builtin_amdgcn_global_load_lds(
      (const __attribute__((address_space(1))) void*)g,
      (__attribute__((address_space(3))) void*)l, 16, 0, 0);
}

// ---------------------------------------------------------------- cast f32 -> bf16
__global__ __launch_bounds__(256) void cast_bf16_kernel(const float* __restrict__ in,
                                                        u16* __restrict__ out, int n4) {
  int i = blockIdx.x * 256 + threadIdx.x;
  if (i >= n4) return;
  float4 v = ((const float4*)in)[i];
  ushort4 o;
  o.x = f32_to_bf16(v.x); o.y = f32_to_bf16(v.y);
  o.z = f32_to_bf16(v.z); o.w = f32_to_bf16(v.w);
  ((ushort4*)out)[i] = o;
}

// ------------------------------------------- transpose + cast: out[c][r] = in[r][c]
__global__ void transpose_cast_kernel(const float* __restrict__ in, u16* __restrict__ out,
                                      int R, int Cc) {
  __shared__ float tile[32][33];
  int c0 = blockIdx.x * 32, r0 = blockIdx.y * 32;
  int tx = threadIdx.x, ty = threadIdx.y;   // 32 x 8
  #pragma unroll
  for (int i = 0; i < 32; i += 8)
    tile[ty + i][tx] = in[(size_t)(r0 + ty + i) * Cc + c0 + tx];
  __syncthreads();
  #pragma unroll
  for (int i = 0; i < 32; i += 8)
    out[(size_t)(c0 + ty + i) * R + r0 + tx] = f32_to_bf16(tile[tx][ty + i]);
}

// ---------------------------------------------------------------- K repack
// Lane-linear fragment tiles: per (bh, 32-kv chunk): 4 frags (t,i), each 64
// lanes x 16B; lane l holds K[kv0 + t*16 + (l&15)][i*32 + (l>>4)*8 .. +8].
__global__ __launch_bounds__(256) void repack_k_kernel(const u16* __restrict__ QKV,
                                                       u16* __restrict__ Kc) {
  const int kvt32 = blockIdx.x, bh = blockIdx.y;
  const int b = bh >> 4, h = bh & 15;
  const int tid = threadIdx.x;
  const int f = tid >> 6, l = tid & 63;
  const int t = f >> 1, i = f & 1;
  const int row = kvt32 * 32 + t * 16 + (l & 15);
  const bf16x8 v = *(const bf16x8*)(QKV + (size_t)b * SEQ_T * QKVC + (size_t)row * QKVC +
                                    CDIM + h * 64 + i * 32 + (l >> 4) * 8);
  *(bf16x8*)(Kc + (size_t)bh * 131072 + (size_t)kvt32 * 2048 + f * 512 + l * 8) = v;
}

// ---------------------------------------------------------------- V repack
// Lane-linear: per (bh, 32-kv chunk): 4 d-frags; lane l = (lhi=l>>4, l15=l&15)
// holds V[kv0 + lhi*8 + j][d*16 + l15], at frag*1KB + lane*16B.
__global__ void repack_v_kernel(const u16* __restrict__ QKV, u16* __restrict__ Vc) {
  __shared__ u16 tile[32][34];
  const int t0 = blockIdx.x * 32, d0 = blockIdx.y * 32;
  const int bh = blockIdx.z;
  const int b = bh >> 4, h = bh & 15;
  const int tx = threadIdx.x, ty = threadIdx.y;   // 32 x 8
  const u16* Vp = QKV + (size_t)b * SEQ_T * QKVC + 2 * CDIM + h * 64 + d0;
  #pragma unroll
  for (int i = 0; i < 32; i += 8)
    tile[ty + i][tx] = Vp[(size_t)(t0 + ty + i) * QKVC + tx];
  __syncthreads();
  const int tid = ty * 32 + tx;
  if (tid < 128) {
    const int bc = tid >> 2, ag = tid & 3;        // bc: d-col 0..31, ag: kv-octet 0..3
    union { u16 u[8]; bf16x8 v; } o;
    #pragma unroll
    for (int j = 0; j < 8; ++j) o.u[j] = tile[ag * 8 + j][bc];
    const int dvl = d0 + bc;
    *(bf16x8*)(Vc + (size_t)bh * 131072 + (size_t)(t0 >> 5) * 2048 +
               (dvl >> 4) * 512 + ag * 128 + (dvl & 15) * 8) = o.v;
  }
}

// ---------------------------------------------------------------- bf16 MFMA GEMM
// Round-9 pipelined 128x128 GEMM, BK=32, K=1024 (NKT=32): triple-buffered LDS,
// counted vmcnt(4) + raw barrier, chunk-rotation swizzle, setprio MFMA cluster.
template <typename OT, bool QSCALE>
__global__ __launch_bounds__(256, 3)
void gemm_bt_kernel(const u16* __restrict__ A, const u16* __restrict__ Bt,
                    OT* __restrict__ C, int N, int K) {
  __shared__ u16 sA[3][4096];
  __shared__ u16 sB[3][4096];
  const int tid = threadIdx.x;
  const int lane = tid & 63, w = tid >> 6;
  const int wm = w >> 1, wn = w & 1;
  const int l15 = lane & 15, lhi = lane >> 4;
  const int row0 = blockIdx.x * 128, col0 = blockIdx.y * 128;

  const int oln  = ((lane & 3) - (lane >> 2)) & 3;
  const int srow = w * 32 + (lane >> 2);
  const u16* aS = A  + (size_t)(row0 + srow) * K + oln * 8;
  const u16* bS = Bt + (size_t)(col0 + srow) * K + oln * 8;
  const int stD = w * 1024;
  const int rdA = (wm * 64 + l15) * 32 + ((lhi + l15) & 3) * 8;
  const int rdB = (wn * 64 + l15) * 32 + ((lhi + l15) & 3) * 8;

  f32x4 acc[4][4] = {};

#define STAGE(KT, S)                                                            \
  {                                                                             \
    const size_t ko = (size_t)(KT) * 32;                                        \
    gload_lds16(aS + ko,          &sA[S][stD]);                                 \
    gload_lds16(aS + ko + 16 * K, &sA[S][stD + 512]);                           \
    gload_lds16(bS + ko,          &sB[S][stD]);                                 \
    gload_lds16(bS + ko + 16 * K, &sB[S][stD + 512]);                           \
  }
#define COMPUTE(S)                                                              \
  {                                                                             \
    bf16x8 af[4], bf[4];                                                        \
    _Pragma("unroll") for (int mi = 0; mi < 4; ++mi)                            \
      af[mi] = *(const bf16x8*)&sA[S][rdA + mi * 512];                          \
    _Pragma("unroll") for (int ni = 0; ni < 4; ++ni)                            \
      bf[ni] = *(const bf16x8*)&sB[S][rdB + ni * 512];                          \
    __builtin_amdgcn_s_setprio(1);                                              \
    _Pragma("unroll") for (int mi = 0; mi < 4; ++mi)                            \
      _Pragma("unroll") for (int ni = 0; ni < 4; ++ni)                          \
        acc[mi][ni] = __builtin_amdgcn_mfma_f32_16x16x32_bf16(af[mi], bf[ni],   \
                                                              acc[mi][ni], 0, 0, 0); \
    __builtin_amdgcn_s_setprio(0);                                              \
  }
#define WAITBAR4                                                                \
  asm volatile("s_waitcnt vmcnt(4)" ::: "memory");                              \
  __builtin_amdgcn_sched_barrier(0);                                            \
  __builtin_amdgcn_s_barrier();

  STAGE(0, 0);
  STAGE(1, 1);
  WAITBAR4;

  #pragma unroll 1
  for (int kt = 0; kt < 30; kt += 3) {
    STAGE(kt + 2, 2); COMPUTE(0); WAITBAR4;
    STAGE(kt + 3, 0); COMPUTE(1); WAITBAR4;
    STAGE(kt + 4, 1); COMPUTE(2); WAITBAR4;
  }
  COMPUTE(0);
  asm volatile("s_waitcnt vmcnt(0)" ::: "memory");
  __builtin_amdgcn_sched_barrier(0);
  __builtin_amdgcn_s_barrier();
  COMPUTE(1);
#undef STAGE
#undef COMPUTE
#undef WAITBAR4

  #pragma unroll
  for (int mt = 0; mt < 4; ++mt)
    #pragma unroll
    for (int nt = 0; nt < 4; ++nt)
      #pragma unroll
      for (int r = 0; r < 4; ++r) {
        const int rr = row0 + wm * 64 + mt * 16 + lhi * 4 + r;
        const int cc = col0 + wn * 64 + nt * 16 + l15;
        float v = acc[mt][nt][r];
        if (QSCALE && cc < CDIM) v *= 0.18033688011f;   // 0.125 * log2(e)
        if constexpr (sizeof(OT) == 2) C[(size_t)rr * N + cc] = f32_to_bf16(v);
        else                           C[(size_t)rr * N + cc] = v;
      }
}

// ---------------------------------------------------------------- flash attention
// Round-14: UN-PAIRED JOBS -> 2x WAVES.  One 16-row job per wave (8192 waves,
// grid 2048, launch_bounds(256,6) = 85-reg budget, up to 24 waves/CU vs the
// paired structure's hard 16-wave cap).  Attacks the measured latency stall:
// only 4 waves/SIMD covered each step's ~300cy dependent chain (ds_read ->
// QK mfma -> exp2 -> cvt/permlane -> PV mfma).  Block = 4 waves covering jobs
// {2g, 2g+1, 127-2g, 126-2g} of one (b,h); LDS staging still block-shared and
// block-uniform (ncmax = 64-g); ds_reads + step guarded by ic < nch.
template <bool DOMASK>
__device__ __forceinline__ void attn_step(const bf16x8 (&qf)[2],
                                          const bf16x8 (&kf)[2][2],
                                          const bf16x8 (&vb)[4],
                                          const bf16x8 ones,
                                          f32x4 (&acc)[4], f32x4& acc1,
                                          int l15, int lhi, int kv0, int qg) {
  f32x4 st[2];
  #pragma unroll
  for (int t = 0; t < 2; ++t) {
    f32x4 z = {0.f, 0.f, 0.f, 0.f};
    z = __builtin_amdgcn_mfma_f32_16x16x32_bf16(kf[t][0], qf[0], z, 0, 0, 0);
    z = __builtin_amdgcn_mfma_f32_16x16x32_bf16(kf[t][1], qf[1], z, 0, 0, 0);
    st[t] = z;
  }
  #pragma unroll
  for (int t = 0; t < 2; ++t)
    #pragma unroll
    for (int r = 0; r < 4; ++r) {
      float sv = st[t][r];                       // Q pre-scaled: log2-domain score
      if (DOMASK) {
        const int kvg = kv0 + t * 16 + lhi * 4 + r;
        sv = (kvg > qg) ? -__builtin_inff() : sv;
      }
      st[t][r] = exp2f(sv);
    }
  // In-register P^T -> PA transpose among the 4 lane-groups sharing l15.
  unsigned c00, c01, c10, c11;
  asm("v_cvt_pk_bf16_f32 %0, %1, %2" : "=v"(c00) : "v"(st[0][0]), "v"(st[0][1]));
  asm("v_cvt_pk_bf16_f32 %0, %1, %2" : "=v"(c01) : "v"(st[0][2]), "v"(st[0][3]));
  asm("v_cvt_pk_bf16_f32 %0, %1, %2" : "=v"(c10) : "v"(st[1][0]), "v"(st[1][1]));
  asm("v_cvt_pk_bf16_f32 %0, %1, %2" : "=v"(c11) : "v"(st[1][2]), "v"(st[1][3]));
  asm("v_permlane32_swap_b32 %0, %1" : "+v"(c00), "+v"(c10));
  asm("v_permlane32_swap_b32 %0, %1" : "+v"(c01), "+v"(c11));
  asm("v_permlane16_swap_b32 %0, %1" : "+v"(c00), "+v"(c10));
  asm("v_permlane16_swap_b32 %0, %1" : "+v"(c01), "+v"(c11));
  uint32x4 pw; pw[0] = c00; pw[1] = c01; pw[2] = c10; pw[3] = c11;
  const bf16x8 pa = __builtin_bit_cast(bf16x8, pw);
  #pragma unroll
  for (int d = 0; d < 4; ++d)
    acc[d] = __builtin_amdgcn_mfma_f32_16x16x32_bf16(pa, vb[d], acc[d], 0, 0, 0);
  acc1 = __builtin_amdgcn_mfma_f32_16x16x32_bf16(pa, ones, acc1, 0, 0, 0);
}

__global__ __launch_bounds__(256, 6) void attn_kernel(const u16* __restrict__ QKV,
                                                      const u16* __restrict__ Kc,
                                                      const u16* __restrict__ Vc,
                                                      u16* __restrict__ Y) {
  __shared__ u16 Kl[2][2048];     // [buf][4 frags x 64 lanes x 8 u16] = 4KB each
  __shared__ u16 Vl[2][2048];
  const int tid = threadIdx.x, lane = tid & 63, wid = tid >> 6;
  const int l15 = lane & 15, lhi = lane >> 4;
  // decode: id = xcd + 8*g + 256*hi3; bh = hi3*8 + xcd (all g-blocks of a bh
  // share an XCD under round-robin; harmless otherwise).
  const int id = blockIdx.x;
  const int xcd = id & 7, g = (id >> 3) & 31, hi3 = id >> 8;
  const int bh = hi3 * 8 + xcd;
  const int b = bh >> 4, h = bh & 15;
  // one job per wave: {2g, 2g+1, 127-2g, 126-2g}
  const int jw = (wid == 0) ? 2 * g : (wid == 1) ? 2 * g + 1
               : (wid == 2) ? 127 - 2 * g : 126 - 2 * g;
  const int q0 = jw * 16;
  const int nch = jw / 2 + 1;                    // chunks this job needs
  const int ncmax = 64 - g;                      // block-uniform chunk count
  const size_t base = (size_t)b * SEQ_T * QKVC;
  const u16* Qp  = QKV + base + h * 64;
  const u16* KcC = Kc + (size_t)bh * 131072;
  const u16* VcC = Vc + (size_t)bh * 131072;

  // ones fragment for the rowsum MFMA (bf16 1.0 = 0x3F80)
  u16x8 ou;
  #pragma unroll
  for (int j = 0; j < 8; ++j) ou[j] = 0x3F80;
  const bf16x8 ones = __builtin_bit_cast(bf16x8, ou);

  // stage chunk 0 (each wave: 1KB of K + 1KB of V)
  gload_lds16(KcC + wid * 512 + lane * 8, &Kl[0][wid * 512]);
  gload_lds16(VcC + wid * 512 + lane * 8, &Vl[0][wid * 512]);

  bf16x8 qf[2];
  #pragma unroll
  for (int i = 0; i < 2; ++i)
    qf[i] = *(const bf16x8*)(Qp + (size_t)(q0 + l15) * QKVC + i * 32 + lhi * 8);
  const int qg = q0 + l15;

  f32x4 acc[4] = {};
  f32x4 acc1 = {};

  // prologue drain: chunk-0 staging (and Q loads) complete, publish to block
  asm volatile("s_waitcnt vmcnt(0)" ::: "memory");
  __builtin_amdgcn_sched_barrier(0);
  __builtin_amdgcn_s_barrier();

  int cbuf = 0;
  #pragma unroll 1
  for (int ic = 0; ic < ncmax; ++ic) {
    // prefetch next chunk (block-uniform), wait only the pair from last iter
    if (ic + 1 < ncmax) {
      const u16* kg = KcC + (size_t)(ic + 1) * 2048 + wid * 512 + lane * 8;
      const u16* vg = VcC + (size_t)(ic + 1) * 2048 + wid * 512 + lane * 8;
      gload_lds16(kg, &Kl[cbuf ^ 1][wid * 512]);
      gload_lds16(vg, &Vl[cbuf ^ 1][wid * 512]);
      asm volatile("s_waitcnt vmcnt(2)" ::: "memory");
    } else {
      asm volatile("s_waitcnt vmcnt(0)" ::: "memory");
    }
    __builtin_amdgcn_sched_barrier(0);
    __builtin_amdgcn_s_barrier();      // chunk ic visible to all waves

    if (ic < nch) {
      const u16* kb = &Kl[cbuf][0];
      const u16* vp = &Vl[cbuf][0];
      bf16x8 kf[2][2], vb[4];
      #pragma unroll
      for (int t = 0; t < 2; ++t)
        #pragma unroll
        for (int i = 0; i < 2; ++i)
          kf[t][i] = *(const bf16x8*)(kb + (t * 2 + i) * 512 + lane * 8);
      #pragma unroll
      for (int d = 0; d < 4; ++d)
        vb[d] = *(const bf16x8*)(vp + d * 512 + lane * 8);

      const int kv0 = ic * 32;
      if (ic == nch - 1)
        attn_step<true>(qf, kf, vb, ones, acc, acc1, l15, lhi, kv0, qg);
      else
        attn_step<false>(qf, kf, vb, ones, acc, acc1, l15, lhi, kv0, qg);
    }
    __builtin_amdgcn_s_barrier();      // all reads of buf cur done (no drain)
    cbuf ^= 1;
  }

  // epilogue: rowsum already in the right lane/reg (acc1[r]) - no shuffles
  u16* Yp = Y + (size_t)b * SEQ_T * CDIM + h * 64;
  #pragma unroll
  for (int r = 0; r < 4; ++r) {
    const float iv = 1.0f / acc1[r];
    #pragma unroll
    for (int d = 0; d < 4; ++d)
      Yp[(size_t)(q0 + lhi * 4 + r) * CDIM + d * 16 + l15] = f32_to_bf16(acc[d][r] * iv);
  }
}

// ---------------------------------------------------------------- launch
extern "C" void kernel_launch(void* const* d_in, const int* in_sizes, int n_in,
                              void* d_out, int out_size, void* d_ws, size_t ws_size,
                              hipStream_t stream) {
  const float* x      = (const float*)d_in[0];
  const float* w_qkv  = (const float*)d_in[1];
  const float* w_proj = (const float*)d_in[2];
  float* out = (float*)d_out;

  u16* Xb  = (u16*)d_ws;                                // 8192*1024 bf16 (dead after GEMM1)
  u16* Wqt = Xb  + (size_t)MROWS * CDIM;                // 3072*1024
  u16* Wpt = Wqt + (size_t)QKVC * CDIM;                 // 1024*1024
  u16* QKV = Wpt + (size_t)CDIM * CDIM;                 // 8192*3072
  u16* Yb  = QKV + (size_t)MROWS * QKVC;                // 8192*1024
  u16* Vc  = Yb  + (size_t)MROWS * CDIM;                // 64*131072 (blocked V)
  u16* Kc  = Xb;                                        // 64*131072 (blocked K, aliases Xb)

  // casts / transposes
  cast_bf16_kernel<<<(MROWS * CDIM / 4 + 255) / 256, 256, 0, stream>>>(x, Xb, MROWS * CDIM / 4);
  transpose_cast_kernel<<<dim3(QKVC / 32, CDIM / 32), dim3(32, 8), 0, stream>>>(w_qkv, Wqt, CDIM, QKVC);
  transpose_cast_kernel<<<dim3(CDIM / 32, CDIM / 32), dim3(32, 8), 0, stream>>>(w_proj, Wpt, CDIM, CDIM);

  // qkv = x @ w_qkv  (bf16 out; Q columns pre-scaled by 0.125*log2e)
  gemm_bt_kernel<u16, true><<<dim3(MROWS / 128, QKVC / 128), 256, 0, stream>>>(Xb, Wqt, QKV, QKVC, CDIM);

  // K/V repack into lane-linear fragment tiles (Kc overwrites Xb - safe after GEMM1)
  repack_k_kernel<<<dim3(SEQ_T / 32, NBATCH * NHEAD), 256, 0, stream>>>(QKV, Kc);
  repack_v_kernel<<<dim3(SEQ_T / 32, 2, NBATCH * NHEAD), dim3(32, 8), 0, stream>>>(QKV, Vc);

  // attention (un-paired: 1 job/wave, 8192 waves, 2048 blocks, 6 waves/SIMD cap)
  attn_kernel<<<2048, 256, 0, stream>>>(QKV, Kc, Vc, Yb);

  // out = y @ w_proj  (f32 out)
  gemm_bt_kernel<float, false><<<dim3(MROWS / 128, CDIM / 128), 256, 0, stream>>>(Yb, Wpt, out, CDIM, CDIM);
}

// Round 15
// 202.960 us; speedup vs baseline: 1.0069x; 1.0069x over previous
//
#include <hip/hip_runtime.h>

// Problem constants (B,T,C,H,Dh) = (4,2048,1024,16,64); M = B*T = 8192.
#define SEQ_T 2048
#define NBATCH 4
#define CDIM 1024
#define NHEAD 16
#define MROWS 8192      // NBATCH * SEQ_T
#define QKVC 3072       // 3*CDIM

typedef unsigned short u16;
typedef __bf16 bf16x8 __attribute__((ext_vector_type(8)));
typedef float f32x4 __attribute__((ext_vector_type(4)));
typedef unsigned short u16x8 __attribute__((ext_vector_type(8)));
typedef unsigned uint32x4 __attribute__((ext_vector_type(4)));

__device__ __forceinline__ u16 f32_to_bf16(float f) {
  union { float f; unsigned int u; } v; v.f = f;
  unsigned int u = v.u;
  unsigned int r = ((u >> 16) & 1u) + 0x7fffu;   // round-to-nearest-even
  return (u16)((u + r) >> 16);
}

__device__ __forceinline__ void gload_lds16(const u16* g, u16* l) {
  __builtin_amdgcn_global_load_lds(
      (const __attribute__((address_space(1))) void*)g,
      (__attribute__((address_space(3))) void*)l, 16, 0, 0);
}

// ---------------------------------------------------------------- cast f32 -> bf16
__global__ __launch_bounds__(256) void cast_bf16_kernel(const float* __restrict__ in,
                                                        u16* __restrict__ out, int n4) {
  int i = blockIdx.x * 256 + threadIdx.x;
  if (i >= n4) return;
  float4 v = ((const float4*)in)[i];
  ushort4 o;
  o.x = f32_to_bf16(v.x); o.y = f32_to_bf16(v.y);
  o.z = f32_to_bf16(v.z); o.w = f32_to_bf16(v.w);
  ((ushort4*)out)[i] = o;
}

// ------------------------------------------- transpose + cast: out[c][r] = in[r][c]
__global__ void transpose_cast_kernel(const float* __restrict__ in, u16* __restrict__ out,
                                      int R, int Cc) {
  __shared__ float tile[32][33];
  int c0 = blockIdx.x * 32, r0 = blockIdx.y * 32;
  int tx = threadIdx.x, ty = threadIdx.y;   // 32 x 8
  #pragma unroll
  for (int i = 0; i < 32; i += 8)
    tile[ty + i][tx] = in[(size_t)(r0 + ty + i) * Cc + c0 + tx];
  __syncthreads();
  #pragma unroll
  for (int i = 0; i < 32; i += 8)
    out[(size_t)(c0 + ty + i) * R + r0 + tx] = f32_to_bf16(tile[tx][ty + i]);
}

// ---------------------------------------------------------------- K repack
// Lane-linear fragment tiles: per (bh, 32-kv chunk): 4 frags (t,i), each 64
// lanes x 16B; lane l holds K[kv0 + t*16 + (l&15)][i*32 + (l>>4)*8 .. +8].
__global__ __launch_bounds__(256) void repack_k_kernel(const u16* __restrict__ QKV,
                                                       u16* __restrict__ Kc) {
  const int kvt32 = blockIdx.x, bh = blockIdx.y;
  const int b = bh >> 4, h = bh & 15;
  const int tid = threadIdx.x;
  const int f = tid >> 6, l = tid & 63;
  const int t = f >> 1, i = f & 1;
  const int row = kvt32 * 32 + t * 16 + (l & 15);
  const bf16x8 v = *(const bf16x8*)(QKV + (size_t)b * SEQ_T * QKVC + (size_t)row * QKVC +
                                    CDIM + h * 64 + i * 32 + (l >> 4) * 8);
  *(bf16x8*)(Kc + (size_t)bh * 131072 + (size_t)kvt32 * 2048 + f * 512 + l * 8) = v;
}

// ---------------------------------------------------------------- V repack
// Lane-linear: per (bh, 32-kv chunk): 4 d-frags; lane l = (lhi=l>>4, l15=l&15)
// holds V[kv0 + lhi*8 + j][d*16 + l15], at frag*1KB + lane*16B.
__global__ void repack_v_kernel(const u16* __restrict__ QKV, u16* __restrict__ Vc) {
  __shared__ u16 tile[32][34];
  const int t0 = blockIdx.x * 32, d0 = blockIdx.y * 32;
  const int bh = blockIdx.z;
  const int b = bh >> 4, h = bh & 15;
  const int tx = threadIdx.x, ty = threadIdx.y;   // 32 x 8
  const u16* Vp = QKV + (size_t)b * SEQ_T * QKVC + 2 * CDIM + h * 64 + d0;
  #pragma unroll
  for (int i = 0; i < 32; i += 8)
    tile[ty + i][tx] = Vp[(size_t)(t0 + ty + i) * QKVC + tx];
  __syncthreads();
  const int tid = ty * 32 + tx;
  if (tid < 128) {
    const int bc = tid >> 2, ag = tid & 3;        // bc: d-col 0..31, ag: kv-octet 0..3
    union { u16 u[8]; bf16x8 v; } o;
    #pragma unroll
    for (int j = 0; j < 8; ++j) o.u[j] = tile[ag * 8 + j][bc];
    const int dvl = d0 + bc;
    *(bf16x8*)(Vc + (size_t)bh * 131072 + (size_t)(t0 >> 5) * 2048 +
               (dvl >> 4) * 512 + ag * 128 + (dvl & 15) * 8) = o.v;
  }
}

// ---------------------------------------------------------------- bf16 MFMA GEMM
// Round-9 pipelined 128x128 GEMM, BK=32, K=1024 (NKT=32): triple-buffered LDS,
// counted vmcnt(4) + raw barrier, chunk-rotation swizzle, setprio MFMA cluster.
template <typename OT, bool QSCALE>
__global__ __launch_bounds__(256, 3)
void gemm_bt_kernel(const u16* __restrict__ A, const u16* __restrict__ Bt,
                    OT* __restrict__ C, int N, int K) {
  __shared__ u16 sA[3][4096];
  __shared__ u16 sB[3][4096];
  const int tid = threadIdx.x;
  const int lane = tid & 63, w = tid >> 6;
  const int wm = w >> 1, wn = w & 1;
  const int l15 = lane & 15, lhi = lane >> 4;
  const int row0 = blockIdx.x * 128, col0 = blockIdx.y * 128;

  const int oln  = ((lane & 3) - (lane >> 2)) & 3;
  const int srow = w * 32 + (lane >> 2);
  const u16* aS = A  + (size_t)(row0 + srow) * K + oln * 8;
  const u16* bS = Bt + (size_t)(col0 + srow) * K + oln * 8;
  const int stD = w * 1024;
  const int rdA = (wm * 64 + l15) * 32 + ((lhi + l15) & 3) * 8;
  const int rdB = (wn * 64 + l15) * 32 + ((lhi + l15) & 3) * 8;

  f32x4 acc[4][4] = {};

#define STAGE(KT, S)                                                            \
  {                                                                             \
    const size_t ko = (size_t)(KT) * 32;                                        \
    gload_lds16(aS + ko,          &sA[S][stD]);                                 \
    gload_lds16(aS + ko + 16 * K, &sA[S][stD + 512]);                           \
    gload_lds16(bS + ko,          &sB[S][stD]);                                 \
    gload_lds16(bS + ko + 16 * K, &sB[S][stD + 512]);                           \
  }
#define COMPUTE(S)                                                              \
  {                                                                             \
    bf16x8 af[4], bf[4];                                                        \
    _Pragma("unroll") for (int mi = 0; mi < 4; ++mi)                            \
      af[mi] = *(const bf16x8*)&sA[S][rdA + mi * 512];                          \
    _Pragma("unroll") for (int ni = 0; ni < 4; ++ni)                            \
      bf[ni] = *(const bf16x8*)&sB[S][rdB + ni * 512];                          \
    __builtin_amdgcn_s_setprio(1);                                              \
    _Pragma("unroll") for (int mi = 0; mi < 4; ++mi)                            \
      _Pragma("unroll") for (int ni = 0; ni < 4; ++ni)                          \
        acc[mi][ni] = __builtin_amdgcn_mfma_f32_16x16x32_bf16(af[mi], bf[ni],   \
                                                              acc[mi][ni], 0, 0, 0); \
    __builtin_amdgcn_s_setprio(0);                                              \
  }
#define WAITBAR4                                                                \
  asm volatile("s_waitcnt vmcnt(4)" ::: "memory");                              \
  __builtin_amdgcn_sched_barrier(0);                                            \
  __builtin_amdgcn_s_barrier();

  STAGE(0, 0);
  STAGE(1, 1);
  WAITBAR4;

  #pragma unroll 1
  for (int kt = 0; kt < 30; kt += 3) {
    STAGE(kt + 2, 2); COMPUTE(0); WAITBAR4;
    STAGE(kt + 3, 0); COMPUTE(1); WAITBAR4;
    STAGE(kt + 4, 1); COMPUTE(2); WAITBAR4;
  }
  COMPUTE(0);
  asm volatile("s_waitcnt vmcnt(0)" ::: "memory");
  __builtin_amdgcn_sched_barrier(0);
  __builtin_amdgcn_s_barrier();
  COMPUTE(1);
#undef STAGE
#undef COMPUTE
#undef WAITBAR4

  #pragma unroll
  for (int mt = 0; mt < 4; ++mt)
    #pragma unroll
    for (int nt = 0; nt < 4; ++nt)
      #pragma unroll
      for (int r = 0; r < 4; ++r) {
        const int rr = row0 + wm * 64 + mt * 16 + lhi * 4 + r;
        const int cc = col0 + wn * 64 + nt * 16 + l15;
        float v = acc[mt][nt][r];
        if (QSCALE && cc < CDIM) v *= 0.18033688011f;   // 0.125 * log2(e)
        if constexpr (sizeof(OT) == 2) C[(size_t)rr * N + cc] = f32_to_bf16(v);
        else                           C[(size_t)rr * N + cc] = v;
      }
}

// ---------------------------------------------------------------- flash attention
// Round-15: round-14 un-paired structure with __launch_bounds__(256,5) (~102-reg
// budget) instead of (256,6) (85).  Round 14's regression was register
// starvation (VGPR_Count 40 -> AGPR shuttling of K/V fragments), which
// confounded the occupancy test (occ DID rise 30->41%).  At 102 regs the
// un-paired live set (~80) fits in arch VGPRs; occupancy cap 20 waves/CU.
template <bool DOMASK>
__device__ __forceinline__ void attn_step(const bf16x8 (&qf)[2],
                                          const bf16x8 (&kf)[2][2],
                                          const bf16x8 (&vb)[4],
                                          const bf16x8 ones,
                                          f32x4 (&acc)[4], f32x4& acc1,
                                          int l15, int lhi, int kv0, int qg) {
  f32x4 st[2];
  #pragma unroll
  for (int t = 0; t < 2; ++t) {
    f32x4 z = {0.f, 0.f, 0.f, 0.f};
    z = __builtin_amdgcn_mfma_f32_16x16x32_bf16(kf[t][0], qf[0], z, 0, 0, 0);
    z = __builtin_amdgcn_mfma_f32_16x16x32_bf16(kf[t][1], qf[1], z, 0, 0, 0);
    st[t] = z;
  }
  #pragma unroll
  for (int t = 0; t < 2; ++t)
    #pragma unroll
    for (int r = 0; r < 4; ++r) {
      float sv = st[t][r];                       // Q pre-scaled: log2-domain score
      if (DOMASK) {
        const int kvg = kv0 + t * 16 + lhi * 4 + r;
        sv = (kvg > qg) ? -__builtin_inff() : sv;
      }
      st[t][r] = exp2f(sv);
    }
  // In-register P^T -> PA transpose among the 4 lane-groups sharing l15.
  unsigned c00, c01, c10, c11;
  asm("v_cvt_pk_bf16_f32 %0, %1, %2" : "=v"(c00) : "v"(st[0][0]), "v"(st[0][1]));
  asm("v_cvt_pk_bf16_f32 %0, %1, %2" : "=v"(c01) : "v"(st[0][2]), "v"(st[0][3]));
  asm("v_cvt_pk_bf16_f32 %0, %1, %2" : "=v"(c10) : "v"(st[1][0]), "v"(st[1][1]));
  asm("v_cvt_pk_bf16_f32 %0, %1, %2" : "=v"(c11) : "v"(st[1][2]), "v"(st[1][3]));
  asm("v_permlane32_swap_b32 %0, %1" : "+v"(c00), "+v"(c10));
  asm("v_permlane32_swap_b32 %0, %1" : "+v"(c01), "+v"(c11));
  asm("v_permlane16_swap_b32 %0, %1" : "+v"(c00), "+v"(c10));
  asm("v_permlane16_swap_b32 %0, %1" : "+v"(c01), "+v"(c11));
  uint32x4 pw; pw[0] = c00; pw[1] = c01; pw[2] = c10; pw[3] = c11;
  const bf16x8 pa = __builtin_bit_cast(bf16x8, pw);
  #pragma unroll
  for (int d = 0; d < 4; ++d)
    acc[d] = __builtin_amdgcn_mfma_f32_16x16x32_bf16(pa, vb[d], acc[d], 0, 0, 0);
  acc1 = __builtin_amdgcn_mfma_f32_16x16x32_bf16(pa, ones, acc1, 0, 0, 0);
}

__global__ __launch_bounds__(256, 5) void attn_kernel(const u16* __restrict__ QKV,
                                                      const u16* __restrict__ Kc,
                                                      const u16* __restrict__ Vc,
                                                      u16* __restrict__ Y) {
  __shared__ u16 Kl[2][2048];     // [buf][4 frags x 64 lanes x 8 u16] = 4KB each
  __shared__ u16 Vl[2][2048];
  const int tid = threadIdx.x, lane = tid & 63, wid = tid >> 6;
  const int l15 = lane & 15, lhi = lane >> 4;
  // decode: id = xcd + 8*g + 256*hi3; bh = hi3*8 + xcd (all g-blocks of a bh
  // share an XCD under round-robin; harmless otherwise).
  const int id = blockIdx.x;
  const int xcd = id & 7, g = (id >> 3) & 31, hi3 = id >> 8;
  const int bh = hi3 * 8 + xcd;
  const int b = bh >> 4, h = bh & 15;
  // one job per wave: {2g, 2g+1, 127-2g, 126-2g}
  const int jw = (wid == 0) ? 2 * g : (wid == 1) ? 2 * g + 1
               : (wid == 2) ? 127 - 2 * g : 126 - 2 * g;
  const int q0 = jw * 16;
  const int nch = jw / 2 + 1;                    // chunks this job needs
  const int ncmax = 64 - g;                      // block-uniform chunk count
  const size_t base = (size_t)b * SEQ_T * QKVC;
  const u16* Qp  = QKV + base + h * 64;
  const u16* KcC = Kc + (size_t)bh * 131072;
  const u16* VcC = Vc + (size_t)bh * 131072;

  // ones fragment for the rowsum MFMA (bf16 1.0 = 0x3F80)
  u16x8 ou;
  #pragma unroll
  for (int j = 0; j < 8; ++j) ou[j] = 0x3F80;
  const bf16x8 ones = __builtin_bit_cast(bf16x8, ou);

  // stage chunk 0 (each wave: 1KB of K + 1KB of V)
  gload_lds16(KcC + wid * 512 + lane * 8, &Kl[0][wid * 512]);
  gload_lds16(VcC + wid * 512 + lane * 8, &Vl[0][wid * 512]);

  bf16x8 qf[2];
  #pragma unroll
  for (int i = 0; i < 2; ++i)
    qf[i] = *(const bf16x8*)(Qp + (size_t)(q0 + l15) * QKVC + i * 32 + lhi * 8);
  const int qg = q0 + l15;

  f32x4 acc[4] = {};
  f32x4 acc1 = {};

  // prologue drain: chunk-0 staging (and Q loads) complete, publish to block
  asm volatile("s_waitcnt vmcnt(0)" ::: "memory");
  __builtin_amdgcn_sched_barrier(0);
  __builtin_amdgcn_s_barrier();

  int cbuf = 0;
  #pragma unroll 1
  for (int ic = 0; ic < ncmax; ++ic) {
    // prefetch next chunk (block-uniform), wait only the pair from last iter
    if (ic + 1 < ncmax) {
      const u16* kg = KcC + (size_t)(ic + 1) * 2048 + wid * 512 + lane * 8;
      const u16* vg = VcC + (size_t)(ic + 1) * 2048 + wid * 512 + lane * 8;
      gload_lds16(kg, &Kl[cbuf ^ 1][wid * 512]);
      gload_lds16(vg, &Vl[cbuf ^ 1][wid * 512]);
      asm volatile("s_waitcnt vmcnt(2)" ::: "memory");
    } else {
      asm volatile("s_waitcnt vmcnt(0)" ::: "memory");
    }
    __builtin_amdgcn_sched_barrier(0);
    __builtin_amdgcn_s_barrier();      // chunk ic visible to all waves

    if (ic < nch) {
      const u16* kb = &Kl[cbuf][0];
      const u16* vp = &Vl[cbuf][0];
      bf16x8 kf[2][2], vb[4];
      #pragma unroll
      for (int t = 0; t < 2; ++t)
        #pragma unroll
        for (int i = 0; i < 2; ++i)
          kf[t][i] = *(const bf16x8*)(kb + (t * 2 + i) * 512 + lane * 8);
      #pragma unroll
      for (int d = 0; d < 4; ++d)
        vb[d] = *(const bf16x8*)(vp + d * 512 + lane * 8);

      const int kv0 = ic * 32;
      if (ic == nch - 1)
        attn_step<true>(qf, kf, vb, ones, acc, acc1, l15, lhi, kv0, qg);
      else
        attn_step<false>(qf, kf, vb, ones, acc, acc1, l15, lhi, kv0, qg);
    }
    __builtin_amdgcn_s_barrier();      // all reads of buf cur done (no drain)
    cbuf ^= 1;
  }

  // epilogue: rowsum already in the right lane/reg (acc1[r]) - no shuffles
  u16* Yp = Y + (size_t)b * SEQ_T * CDIM + h * 64;
  #pragma unroll
  for (int r = 0; r < 4; ++r) {
    const float iv = 1.0f / acc1[r];
    #pragma unroll
    for (int d = 0; d < 4; ++d)
      Yp[(size_t)(q0 + lhi * 4 + r) * CDIM + d * 16 + l15] = f32_to_bf16(acc[d][r] * iv);
  }
}

// ---------------------------------------------------------------- launch
extern "C" void kernel_launch(void* const* d_in, const int* in_sizes, int n_in,
                              void* d_out, int out_size, void* d_ws, size_t ws_size,
                              hipStream_t stream) {
  const float* x      = (const float*)d_in[0];
  const float* w_qkv  = (const float*)d_in[1];
  const float* w_proj = (const float*)d_in[2];
  float* out = (float*)d_out;

  u16* Xb  = (u16*)d_ws;                                // 8192*1024 bf16 (dead after GEMM1)
  u16* Wqt = Xb  + (size_t)MROWS * CDIM;                // 3072*1024
  u16* Wpt = Wqt + (size_t)QKVC * CDIM;                 // 1024*1024
  u16* QKV = Wpt + (size_t)CDIM * CDIM;                 // 8192*3072
  u16* Yb  = QKV + (size_t)MROWS * QKVC;                // 8192*1024
  u16* Vc  = Yb  + (size_t)MROWS * CDIM;                // 64*131072 (blocked V)
  u16* Kc  = Xb;                                        // 64*131072 (blocked K, aliases Xb)

  // casts / transposes
  cast_bf16_kernel<<<(MROWS * CDIM / 4 + 255) / 256, 256, 0, stream>>>(x, Xb, MROWS * CDIM / 4);
  transpose_cast_kernel<<<dim3(QKVC / 32, CDIM / 32), dim3(32, 8), 0, stream>>>(w_qkv, Wqt, CDIM, QKVC);
  transpose_cast_kernel<<<dim3(CDIM / 32, CDIM / 32), dim3(32, 8), 0, stream>>>(w_proj, Wpt, CDIM, CDIM);

  // qkv = x @ w_qkv  (bf16 out; Q columns pre-scaled by 0.125*log2e)
  gemm_bt_kernel<u16, true><<<dim3(MROWS / 128, QKVC / 128), 256, 0, stream>>>(Xb, Wqt, QKV, QKVC, CDIM);

  // K/V repack into lane-linear fragment tiles (Kc overwrites Xb - safe after GEMM1)
  repack_k_kernel<<<dim3(SEQ_T / 32, NBATCH * NHEAD), 256, 0, stream>>>(QKV, Kc);
  repack_v_kernel<<<dim3(SEQ_T / 32, 2, NBATCH * NHEAD), dim3(32, 8), 0, stream>>>(QKV, Vc);

  // attention (un-paired: 1 job/wave, 8192 waves, 2048 blocks, 5 waves/SIMD cap)
  attn_kernel<<<2048, 256, 0, stream>>>(QKV, Kc, Vc, Yb);

  // out = y @ w_proj  (f32 out)
  gemm_bt_kernel<float, false><<<dim3(MROWS / 128, CDIM / 128), 256, 0, stream>>>(Yb, Wpt, out, CDIM, CDIM);
}

// Round 16
// 194.335 us; speedup vs baseline: 1.0516x; 1.0444x over previous
//
#include <hip/hip_runtime.h>

// Problem constants (B,T,C,H,Dh) = (4,2048,1024,16,64); M = B*T = 8192.
#define SEQ_T 2048
#define NBATCH 4
#define CDIM 1024
#define NHEAD 16
#define MROWS 8192      // NBATCH * SEQ_T
#define QKVC 3072       // 3*CDIM

typedef unsigned short u16;
typedef __bf16 bf16x8 __attribute__((ext_vector_type(8)));
typedef float f32x4 __attribute__((ext_vector_type(4)));
typedef unsigned short u16x8 __attribute__((ext_vector_type(8)));
typedef unsigned uint32x4 __attribute__((ext_vector_type(4)));

__device__ __forceinline__ u16 f32_to_bf16(float f) {
  union { float f; unsigned int u; } v; v.f = f;
  unsigned int u = v.u;
  unsigned int r = ((u >> 16) & 1u) + 0x7fffu;   // round-to-nearest-even
  return (u16)((u + r) >> 16);
}

__device__ __forceinline__ void gload_lds16(const u16* g, u16* l) {
  __builtin_amdgcn_global_load_lds(
      (const __attribute__((address_space(1))) void*)g,
      (__attribute__((address_space(3))) void*)l, 16, 0, 0);
}

// Blocked (MFMA-fragment-ordered) layout over a [R rows][K=1024] bf16 matrix:
// tile (row>>4, k>>5) is 1KB contiguous; within, lane = (row&15) + (((k>>3)&3)<<4)
// holds 8 u16 at j = k&7.  ds_read_b128 at base+lane*16B == exact MFMA fragment.

// -------------------------------------------- cast f32 -> blocked bf16 (for Xb)
__global__ __launch_bounds__(256) void cast_block_kernel(const float* __restrict__ in,
                                                         u16* __restrict__ out) {
  const int i = blockIdx.x * 256 + threadIdx.x;   // over MROWS*CDIM/8
  const int kg = i & 127;                         // k-group of 8 (CDIM/8=128)
  const int row = i >> 7;
  const float4 v0 = ((const float4*)in)[i * 2];
  const float4 v1 = ((const float4*)in)[i * 2 + 1];
  union { u16 u[8]; bf16x8 b; } o;
  o.u[0] = f32_to_bf16(v0.x); o.u[1] = f32_to_bf16(v0.y);
  o.u[2] = f32_to_bf16(v0.z); o.u[3] = f32_to_bf16(v0.w);
  o.u[4] = f32_to_bf16(v1.x); o.u[5] = f32_to_bf16(v1.y);
  o.u[6] = f32_to_bf16(v1.z); o.u[7] = f32_to_bf16(v1.w);
  const int tile = (row >> 4) * 32 + (kg >> 2);   // KT = CDIM/32 = 32
  const int lane = (row & 15) + ((kg & 3) << 4);
  *(bf16x8*)(out + (size_t)tile * 512 + lane * 8) = o.b;
}

// ------------------------- transpose + cast w_qkv [1024][3072] -> blocked [3072][1024]
__global__ void transpose_cast_block_kernel(const float* __restrict__ in,
                                            u16* __restrict__ out) {
  __shared__ float tile[32][33];
  const int c0 = blockIdx.x * 32, r0 = blockIdx.y * 32;   // c over 3072 (N), r over 1024 (K)
  const int tx = threadIdx.x, ty = threadIdx.y;           // 32 x 8
  #pragma unroll
  for (int i = 0; i < 32; i += 8)
    tile[ty + i][tx] = in[(size_t)(r0 + ty + i) * QKVC + c0 + tx];
  __syncthreads();
  const int t = ty * 32 + tx;
  if (t < 128) {
    const int cc = t & 31, kgq = t >> 5;   // kgq: 8-k quarter 0..3
    union { u16 u[8]; bf16x8 b; } o;
    #pragma unroll
    for (int j = 0; j < 8; ++j) o.u[j] = f32_to_bf16(tile[kgq * 8 + j][cc]);
    const int rowN = c0 + cc;
    const int tileI = (rowN >> 4) * 32 + (r0 >> 5);       // r0 multiple of 32
    const int lane = (rowN & 15) + (kgq << 4);            // ((r0+kgq*8)>>3)&3 == kgq
    *(bf16x8*)(out + (size_t)tileI * 512 + lane * 8) = o.b;
  }
}

// ------------------------------------------- transpose + cast (linear, for Wpt)
__global__ void transpose_cast_kernel(const float* __restrict__ in, u16* __restrict__ out,
                                      int R, int Cc) {
  __shared__ float tile[32][33];
  int c0 = blockIdx.x * 32, r0 = blockIdx.y * 32;
  int tx = threadIdx.x, ty = threadIdx.y;   // 32 x 8
  #pragma unroll
  for (int i = 0; i < 32; i += 8)
    tile[ty + i][tx] = in[(size_t)(r0 + ty + i) * Cc + c0 + tx];
  __syncthreads();
  #pragma unroll
  for (int i = 0; i < 32; i += 8)
    out[(size_t)(c0 + ty + i) * R + r0 + tx] = f32_to_bf16(tile[tx][ty + i]);
}

// ---------------------------------------------------------------- K repack
__global__ __launch_bounds__(256) void repack_k_kernel(const u16* __restrict__ QKV,
                                                       u16* __restrict__ Kc) {
  const int kvt32 = blockIdx.x, bh = blockIdx.y;
  const int b = bh >> 4, h = bh & 15;
  const int tid = threadIdx.x;
  const int f = tid >> 6, l = tid & 63;
  const int t = f >> 1, i = f & 1;
  const int row = kvt32 * 32 + t * 16 + (l & 15);
  const bf16x8 v = *(const bf16x8*)(QKV + (size_t)b * SEQ_T * QKVC + (size_t)row * QKVC +
                                    CDIM + h * 64 + i * 32 + (l >> 4) * 8);
  *(bf16x8*)(Kc + (size_t)bh * 131072 + (size_t)kvt32 * 2048 + f * 512 + l * 8) = v;
}

// ---------------------------------------------------------------- V repack
__global__ void repack_v_kernel(const u16* __restrict__ QKV, u16* __restrict__ Vc) {
  __shared__ u16 tile[32][34];
  const int t0 = blockIdx.x * 32, d0 = blockIdx.y * 32;
  const int bh = blockIdx.z;
  const int b = bh >> 4, h = bh & 15;
  const int tx = threadIdx.x, ty = threadIdx.y;   // 32 x 8
  const u16* Vp = QKV + (size_t)b * SEQ_T * QKVC + 2 * CDIM + h * 64 + d0;
  #pragma unroll
  for (int i = 0; i < 32; i += 8)
    tile[ty + i][tx] = Vp[(size_t)(t0 + ty + i) * QKVC + tx];
  __syncthreads();
  const int tid = ty * 32 + tx;
  if (tid < 128) {
    const int bc = tid >> 2, ag = tid & 3;
    union { u16 u[8]; bf16x8 v; } o;
    #pragma unroll
    for (int j = 0; j < 8; ++j) o.u[j] = tile[ag * 8 + j][bc];
    const int dvl = d0 + bc;
    *(bf16x8*)(Vc + (size_t)bh * 131072 + (size_t)(t0 >> 5) * 2048 +
               (dvl >> 4) * 512 + ag * 128 + (dvl & 15) * 8) = o.v;
  }
}

// ------------------------------- GEMM1: 256x256 tile, blocked inputs, 3-slot pipe
// 8 waves (2x4), wave output 128x64 (8x4 frags).  All LDS ops lane-linear
// (fragment-blocked tiles) -> conflict-free, no swizzle.  Counted vmcnt(4) +
// raw barrier (round-9-proven schedule).  K=1024 fixed (KT=32).
template <bool QSCALE>
__global__ __launch_bounds__(512, 2)
void gemm256_kernel(const u16* __restrict__ Ab, const u16* __restrict__ Bb,
                    u16* __restrict__ C, int N) {
  __shared__ u16 sA[3][8192];   // 16 tiles x 512 u16 = 16KB per slot
  __shared__ u16 sB[3][8192];
  const int tid = threadIdx.x;
  const int lane = tid & 63, w = tid >> 6;       // 8 waves
  const int wm = w >> 2, wn = w & 3;
  const int l15 = lane & 15, lhi = lane >> 4;
  const int row0 = blockIdx.x * 256, col0 = blockIdx.y * 256;

  const u16* aT0 = Ab + ((size_t)((row0 >> 4) + w)     * 32) * 512 + lane * 8;
  const u16* aT1 = Ab + ((size_t)((row0 >> 4) + 8 + w) * 32) * 512 + lane * 8;
  const u16* bT0 = Bb + ((size_t)((col0 >> 4) + w)     * 32) * 512 + lane * 8;
  const u16* bT1 = Bb + ((size_t)((col0 >> 4) + 8 + w) * 32) * 512 + lane * 8;

  f32x4 acc[8][4] = {};

#define STAGE(KT, S)                                                            \
  {                                                                             \
    gload_lds16(aT0 + (size_t)(KT) * 512, &sA[S][w * 512]);                     \
    gload_lds16(aT1 + (size_t)(KT) * 512, &sA[S][(8 + w) * 512]);               \
    gload_lds16(bT0 + (size_t)(KT) * 512, &sB[S][w * 512]);                     \
    gload_lds16(bT1 + (size_t)(KT) * 512, &sB[S][(8 + w) * 512]);               \
  }
#define COMPUTE(S)                                                              \
  {                                                                             \
    bf16x8 bf[4];                                                               \
    _Pragma("unroll") for (int ni = 0; ni < 4; ++ni)                            \
      bf[ni] = *(const bf16x8*)&sB[S][(wn * 4 + ni) * 512 + lane * 8];          \
    __builtin_amdgcn_s_setprio(1);                                              \
    _Pragma("unroll") for (int mi = 0; mi < 8; ++mi) {                          \
      const bf16x8 af = *(const bf16x8*)&sA[S][(wm * 8 + mi) * 512 + lane * 8]; \
      _Pragma("unroll") for (int ni = 0; ni < 4; ++ni)                          \
        acc[mi][ni] = __builtin_amdgcn_mfma_f32_16x16x32_bf16(af, bf[ni],       \
                                                              acc[mi][ni], 0, 0, 0); \
    }                                                                           \
    __builtin_amdgcn_s_setprio(0);                                              \
  }
#define WAITBAR4                                                                \
  asm volatile("s_waitcnt vmcnt(4)" ::: "memory");                              \
  __builtin_amdgcn_sched_barrier(0);                                            \
  __builtin_amdgcn_s_barrier();

  STAGE(0, 0);
  STAGE(1, 1);
  WAITBAR4;

  #pragma unroll 1
  for (int kt = 0; kt < 30; kt += 3) {
    STAGE(kt + 2, 2); COMPUTE(0); WAITBAR4;
    STAGE(kt + 3, 0); COMPUTE(1); WAITBAR4;
    STAGE(kt + 4, 1); COMPUTE(2); WAITBAR4;
  }
  COMPUTE(0);
  asm volatile("s_waitcnt vmcnt(0)" ::: "memory");
  __builtin_amdgcn_sched_barrier(0);
  __builtin_amdgcn_s_barrier();
  COMPUTE(1);
#undef STAGE
#undef COMPUTE
#undef WAITBAR4

  #pragma unroll
  for (int mi = 0; mi < 8; ++mi)
    #pragma unroll
    for (int ni = 0; ni < 4; ++ni)
      #pragma unroll
      for (int r = 0; r < 4; ++r) {
        const int rr = row0 + wm * 128 + mi * 16 + lhi * 4 + r;
        const int cc = col0 + wn * 64 + ni * 16 + l15;
        float v = acc[mi][ni][r];
        if (QSCALE && cc < CDIM) v *= 0.18033688011f;   // 0.125 * log2(e)
        C[(size_t)rr * N + cc] = f32_to_bf16(v);
      }
}

// ------------------------------- GEMM2: round-9 128x128 pipelined (linear inputs)
template <typename OT, bool QSCALE>
__global__ __launch_bounds__(256, 3)
void gemm_bt_kernel(const u16* __restrict__ A, const u16* __restrict__ Bt,
                    OT* __restrict__ C, int N, int K) {
  __shared__ u16 sA[3][4096];
  __shared__ u16 sB[3][4096];
  const int tid = threadIdx.x;
  const int lane = tid & 63, w = tid >> 6;
  const int wm = w >> 1, wn = w & 1;
  const int l15 = lane & 15, lhi = lane >> 4;
  const int row0 = blockIdx.x * 128, col0 = blockIdx.y * 128;

  const int oln  = ((lane & 3) - (lane >> 2)) & 3;
  const int srow = w * 32 + (lane >> 2);
  const u16* aS = A  + (size_t)(row0 + srow) * K + oln * 8;
  const u16* bS = Bt + (size_t)(col0 + srow) * K + oln * 8;
  const int stD = w * 1024;
  const int rdA = (wm * 64 + l15) * 32 + ((lhi + l15) & 3) * 8;
  const int rdB = (wn * 64 + l15) * 32 + ((lhi + l15) & 3) * 8;

  f32x4 acc[4][4] = {};

#define STAGE(KT, S)                                                            \
  {                                                                             \
    const size_t ko = (size_t)(KT) * 32;                                        \
    gload_lds16(aS + ko,          &sA[S][stD]);                                 \
    gload_lds16(aS + ko + 16 * K, &sA[S][stD + 512]);                           \
    gload_lds16(bS + ko,          &sB[S][stD]);                                 \
    gload_lds16(bS + ko + 16 * K, &sB[S][stD + 512]);                           \
  }
#define COMPUTE(S)                                                              \
  {                                                                             \
    bf16x8 af[4], bf[4];                                                        \
    _Pragma("unroll") for (int mi = 0; mi < 4; ++mi)                            \
      af[mi] = *(const bf16x8*)&sA[S][rdA + mi * 512];                          \
    _Pragma("unroll") for (int ni = 0; ni < 4; ++ni)                            \
      bf[ni] = *(const bf16x8*)&sB[S][rdB + ni * 512];                          \
    __builtin_amdgcn_s_setprio(1);                                              \
    _Pragma("unroll") for (int mi = 0; mi < 4; ++mi)                            \
      _Pragma("unroll") for (int ni = 0; ni < 4; ++ni)                          \
        acc[mi][ni] = __builtin_amdgcn_mfma_f32_16x16x32_bf16(af[mi], bf[ni],   \
                                                              acc[mi][ni], 0, 0, 0); \
    __builtin_amdgcn_s_setprio(0);                                              \
  }
#define WAITBAR4                                                                \
  asm volatile("s_waitcnt vmcnt(4)" ::: "memory");                              \
  __builtin_amdgcn_sched_barrier(0);                                            \
  __builtin_amdgcn_s_barrier();

  STAGE(0, 0);
  STAGE(1, 1);
  WAITBAR4;

  #pragma unroll 1
  for (int kt = 0; kt < 30; kt += 3) {
    STAGE(kt + 2, 2); COMPUTE(0); WAITBAR4;
    STAGE(kt + 3, 0); COMPUTE(1); WAITBAR4;
    STAGE(kt + 4, 1); COMPUTE(2); WAITBAR4;
  }
  COMPUTE(0);
  asm volatile("s_waitcnt vmcnt(0)" ::: "memory");
  __builtin_amdgcn_sched_barrier(0);
  __builtin_amdgcn_s_barrier();
  COMPUTE(1);
#undef STAGE
#undef COMPUTE
#undef WAITBAR4

  #pragma unroll
  for (int mt = 0; mt < 4; ++mt)
    #pragma unroll
    for (int nt = 0; nt < 4; ++nt)
      #pragma unroll
      for (int r = 0; r < 4; ++r) {
        const int rr = row0 + wm * 64 + mt * 16 + lhi * 4 + r;
        const int cc = col0 + wn * 64 + nt * 16 + l15;
        float v = acc[mt][nt][r];
        if (QSCALE && cc < CDIM) v *= 0.18033688011f;
        if constexpr (sizeof(OT) == 2) C[(size_t)rr * N + cc] = f32_to_bf16(v);
        else                           C[(size_t)rr * N + cc] = v;
      }
}

// ---------------------------------------------------------------- flash attention
// Round-11 checkpoint (best, 80us): paired jobs (4k+w), block-shared LDS staging
// (double-buffered, __syncthreads), in-register P transpose, rowsum-via-MFMA,
// XCD clustering.
template <bool DOMASK>
__device__ __forceinline__ void attn_step(const bf16x8 (&qf)[2],
                                          const bf16x8 (&kf)[2][2],
                                          const bf16x8 (&vb)[4],
                                          const bf16x8 ones,
                                          f32x4 (&acc)[4], f32x4& acc1,
                                          int l15, int lhi, int kv0, int qg) {
  f32x4 st[2];
  #pragma unroll
  for (int t = 0; t < 2; ++t) {
    f32x4 z = {0.f, 0.f, 0.f, 0.f};
    z = __builtin_amdgcn_mfma_f32_16x16x32_bf16(kf[t][0], qf[0], z, 0, 0, 0);
    z = __builtin_amdgcn_mfma_f32_16x16x32_bf16(kf[t][1], qf[1], z, 0, 0, 0);
    st[t] = z;
  }
  #pragma unroll
  for (int t = 0; t < 2; ++t)
    #pragma unroll
    for (int r = 0; r < 4; ++r) {
      float sv = st[t][r];                       // Q pre-scaled: log2-domain score
      if (DOMASK) {
        const int kvg = kv0 + t * 16 + lhi * 4 + r;
        sv = (kvg > qg) ? -__builtin_inff() : sv;
      }
      st[t][r] = exp2f(sv);
    }
  unsigned c00, c01, c10, c11;
  asm("v_cvt_pk_bf16_f32 %0, %1, %2" : "=v"(c00) : "v"(st[0][0]), "v"(st[0][1]));
  asm("v_cvt_pk_bf16_f32 %0, %1, %2" : "=v"(c01) : "v"(st[0][2]), "v"(st[0][3]));
  asm("v_cvt_pk_bf16_f32 %0, %1, %2" : "=v"(c10) : "v"(st[1][0]), "v"(st[1][1]));
  asm("v_cvt_pk_bf16_f32 %0, %1, %2" : "=v"(c11) : "v"(st[1][2]), "v"(st[1][3]));
  asm("v_permlane32_swap_b32 %0, %1" : "+v"(c00), "+v"(c10));
  asm("v_permlane32_swap_b32 %0, %1" : "+v"(c01), "+v"(c11));
  asm("v_permlane16_swap_b32 %0, %1" : "+v"(c00), "+v"(c10));
  asm("v_permlane16_swap_b32 %0, %1" : "+v"(c01), "+v"(c11));
  uint32x4 pw; pw[0] = c00; pw[1] = c01; pw[2] = c10; pw[3] = c11;
  const bf16x8 pa = __builtin_bit_cast(bf16x8, pw);
  #pragma unroll
  for (int d = 0; d < 4; ++d)
    acc[d] = __builtin_amdgcn_mfma_f32_16x16x32_bf16(pa, vb[d], acc[d], 0, 0, 0);
  acc1 = __builtin_amdgcn_mfma_f32_16x16x32_bf16(pa, ones, acc1, 0, 0, 0);
}

__global__ __launch_bounds__(256, 4) void attn_kernel(const u16* __restrict__ QKV,
                                                      const u16* __restrict__ Kc,
                                                      const u16* __restrict__ Vc,
                                                      u16* __restrict__ Y) {
  __shared__ u16 Kl[2][2048];
  __shared__ u16 Vl[2][2048];
  const int tid = threadIdx.x, lane = tid & 63, wid = tid >> 6;
  const int l15 = lane & 15, lhi = lane >> 4;
  const int id = blockIdx.x;
  const int xcd = id & 7, k = (id >> 3) & 15, hi3 = id >> 7;
  const int bh = hi3 * 8 + xcd;
  const int b = bh >> 4, h = bh & 15;
  const int pa = k * 4 + wid;
  const int qA0 = pa * 16, qB0 = (127 - pa) * 16;
  const int nchA = pa / 2 + 1, nchB = (127 - pa) / 2 + 1;
  const int ncmax = (127 - k * 4) / 2 + 1;
  const size_t base = (size_t)b * SEQ_T * QKVC;
  const u16* Qp  = QKV + base + h * 64;
  const u16* KcC = Kc + (size_t)bh * 131072;
  const u16* VcC = Vc + (size_t)bh * 131072;

  u16x8 ou;
  #pragma unroll
  for (int j = 0; j < 8; ++j) ou[j] = 0x3F80;
  const bf16x8 ones = __builtin_bit_cast(bf16x8, ou);

  gload_lds16(KcC + wid * 512 + lane * 8, &Kl[0][wid * 512]);
  gload_lds16(VcC + wid * 512 + lane * 8, &Vl[0][wid * 512]);

  bf16x8 qfA[2], qfB[2];
  #pragma unroll
  for (int i = 0; i < 2; ++i) {
    qfA[i] = *(const bf16x8*)(Qp + (size_t)(qA0 + l15) * QKVC + i * 32 + lhi * 8);
    qfB[i] = *(const bf16x8*)(Qp + (size_t)(qB0 + l15) * QKVC + i * 32 + lhi * 8);
  }
  const int qgA = qA0 + l15, qgB = qB0 + l15;

  f32x4 accA[4] = {}, accB[4] = {};
  f32x4 acc1A = {}, acc1B = {};

  __syncthreads();

  int cbuf = 0;
  for (int ic = 0; ic < ncmax; ++ic) {
    if (ic + 1 < ncmax) {
      const u16* kg = KcC + (size_t)(ic + 1) * 2048 + wid * 512 + lane * 8;
      const u16* vg = VcC + (size_t)(ic + 1) * 2048 + wid * 512 + lane * 8;
      gload_lds16(kg, &Kl[cbuf ^ 1][wid * 512]);
      gload_lds16(vg, &Vl[cbuf ^ 1][wid * 512]);
    }
    const u16* kb = &Kl[cbuf][0];
    const u16* vp = &Vl[cbuf][0];
    bf16x8 kf[2][2], vb[4];
    #pragma unroll
    for (int t = 0; t < 2; ++t)
      #pragma unroll
      for (int i = 0; i < 2; ++i)
        kf[t][i] = *(const bf16x8*)(kb + (t * 2 + i) * 512 + lane * 8);
    #pragma unroll
    for (int d = 0; d < 4; ++d)
      vb[d] = *(const bf16x8*)(vp + d * 512 + lane * 8);

    const int kv0 = ic * 32;
    if (ic < nchB) {
      if (ic == nchB - 1)
        attn_step<true>(qfB, kf, vb, ones, accB, acc1B, l15, lhi, kv0, qgB);
      else
        attn_step<false>(qfB, kf, vb, ones, accB, acc1B, l15, lhi, kv0, qgB);
    }
    if (ic < nchA) {
      if (ic == nchA - 1)
        attn_step<true>(qfA, kf, vb, ones, accA, acc1A, l15, lhi, kv0, qgA);
      else
        attn_step<false>(qfA, kf, vb, ones, accA, acc1A, l15, lhi, kv0, qgA);
    }
    __syncthreads();
    cbuf ^= 1;
  }

  u16* Yp = Y + (size_t)b * SEQ_T * CDIM + h * 64;
  #pragma unroll
  for (int r = 0; r < 4; ++r) {
    const float ivA = 1.0f / acc1A[r];
    const float ivB = 1.0f / acc1B[r];
    #pragma unroll
    for (int d = 0; d < 4; ++d) {
      Yp[(size_t)(qA0 + lhi * 4 + r) * CDIM + d * 16 + l15] = f32_to_bf16(accA[d][r] * ivA);
      Yp[(size_t)(qB0 + lhi * 4 + r) * CDIM + d * 16 + l15] = f32_to_bf16(accB[d][r] * ivB);
    }
  }
}

// ---------------------------------------------------------------- launch
extern "C" void kernel_launch(void* const* d_in, const int* in_sizes, int n_in,
                              void* d_out, int out_size, void* d_ws, size_t ws_size,
                              hipStream_t stream) {
  const float* x      = (const float*)d_in[0];
  const float* w_qkv  = (const float*)d_in[1];
  const float* w_proj = (const float*)d_in[2];
  float* out = (float*)d_out;

  u16* Xb  = (u16*)d_ws;                                // blocked x (dead after GEMM1)
  u16* Wqt = Xb  + (size_t)MROWS * CDIM;                // blocked w_qkv^T
  u16* Wpt = Wqt + (size_t)QKVC * CDIM;                 // linear  w_proj^T
  u16* QKV = Wpt + (size_t)CDIM * CDIM;                 // 8192*3072 linear
  u16* Yb  = QKV + (size_t)MROWS * QKVC;                // 8192*1024 linear
  u16* Vc  = Yb  + (size_t)MROWS * CDIM;                // blocked V
  u16* Kc  = Xb;                                        // blocked K (aliases Xb)

  // casts / transposes
  cast_block_kernel<<<MROWS * CDIM / 8 / 256, 256, 0, stream>>>(x, Xb);
  transpose_cast_block_kernel<<<dim3(QKVC / 32, CDIM / 32), dim3(32, 8), 0, stream>>>(w_qkv, Wqt);
  transpose_cast_kernel<<<dim3(CDIM / 32, CDIM / 32), dim3(32, 8), 0, stream>>>(w_proj, Wpt, CDIM, CDIM);

  // qkv = x @ w_qkv  (256x256 blocked-input pipelined GEMM; Q pre-scaled)
  gemm256_kernel<true><<<dim3(MROWS / 256, QKVC / 256), 512, 0, stream>>>(Xb, Wqt, QKV, QKVC);

  // K/V repack into lane-linear fragment tiles
  repack_k_kernel<<<dim3(SEQ_T / 32, NBATCH * NHEAD), 256, 0, stream>>>(QKV, Kc);
  repack_v_kernel<<<dim3(SEQ_T / 32, 2, NBATCH * NHEAD), dim3(32, 8), 0, stream>>>(QKV, Vc);

  // attention (round-11 checkpoint)
  attn_kernel<<<1024, 256, 0, stream>>>(QKV, Kc, Vc, Yb);

  // out = y @ w_proj  (f32 out, 128x128 pipelined)
  gemm_bt_kernel<float, false><<<dim3(MROWS / 128, CDIM / 128), 256, 0, stream>>>(Yb, Wpt, out, CDIM, CDIM);
}

// Round 17
// 183.339 us; speedup vs baseline: 1.1147x; 1.0600x over previous
//
#include <hip/hip_runtime.h>

// Problem constants (B,T,C,H,Dh) = (4,2048,1024,16,64); M = B*T = 8192.
#define SEQ_T 2048
#define NBATCH 4
#define CDIM 1024
#define NHEAD 16
#define MROWS 8192      // NBATCH * SEQ_T
#define QKVC 3072       // 3*CDIM

typedef unsigned short u16;
typedef __bf16 bf16x8 __attribute__((ext_vector_type(8)));
typedef float f32x4 __attribute__((ext_vector_type(4)));
typedef unsigned short u16x8 __attribute__((ext_vector_type(8)));
typedef unsigned uint32x4 __attribute__((ext_vector_type(4)));

__device__ __forceinline__ u16 f32_to_bf16(float f) {
  union { float f; unsigned int u; } v; v.f = f;
  unsigned int u = v.u;
  unsigned int r = ((u >> 16) & 1u) + 0x7fffu;   // round-to-nearest-even
  return (u16)((u + r) >> 16);
}

__device__ __forceinline__ void gload_lds16(const u16* g, u16* l) {
  __builtin_amdgcn_global_load_lds(
      (const __attribute__((address_space(1))) void*)g,
      (__attribute__((address_space(3))) void*)l, 16, 0, 0);
}

// ---------------------------------------------------------------- cast f32 -> bf16
__global__ __launch_bounds__(256) void cast_bf16_kernel(const float* __restrict__ in,
                                                        u16* __restrict__ out, int n4) {
  int i = blockIdx.x * 256 + threadIdx.x;
  if (i >= n4) return;
  float4 v = ((const float4*)in)[i];
  ushort4 o;
  o.x = f32_to_bf16(v.x); o.y = f32_to_bf16(v.y);
  o.z = f32_to_bf16(v.z); o.w = f32_to_bf16(v.w);
  ((ushort4*)out)[i] = o;
}

// ------------------------------------------- transpose + cast: out[c][r] = in[r][c]
__global__ void transpose_cast_kernel(const float* __restrict__ in, u16* __restrict__ out,
                                      int R, int Cc) {
  __shared__ float tile[32][33];
  int c0 = blockIdx.x * 32, r0 = blockIdx.y * 32;
  int tx = threadIdx.x, ty = threadIdx.y;   // 32 x 8
  #pragma unroll
  for (int i = 0; i < 32; i += 8)
    tile[ty + i][tx] = in[(size_t)(r0 + ty + i) * Cc + c0 + tx];
  __syncthreads();
  #pragma unroll
  for (int i = 0; i < 32; i += 8)
    out[(size_t)(c0 + ty + i) * R + r0 + tx] = f32_to_bf16(tile[tx][ty + i]);
}

// ---------------------------------------------------------------- bf16 MFMA GEMM
// Round-9 pipelined 128x128, BK=32, K=1024 (NKT=32): triple-buffered LDS,
// counted vmcnt(4) + raw barrier, chunk-rotation swizzle, setprio.
// FUSE variant (GEMM1): epilogue routes Q cols -> Qb (scaled), K cols -> Kc
// blocked-fragment layout, V cols -> Vc blocked layout (replaces the repack
// kernels).  Region branch is block-uniform (128-col blocks never straddle
// the 1024-col boundaries).
template <bool FUSE, typename OT>
__global__ __launch_bounds__(256, 3)
void gemm_bt_kernel(const u16* __restrict__ A, const u16* __restrict__ Bt,
                    OT* __restrict__ C, u16* __restrict__ Kc, u16* __restrict__ Vc,
                    int N, int K) {
  __shared__ u16 sA[3][4096];
  __shared__ u16 sB[3][4096];
  const int tid = threadIdx.x;
  const int lane = tid & 63, w = tid >> 6;
  const int wm = w >> 1, wn = w & 1;
  const int l15 = lane & 15, lhi = lane >> 4;
  const int row0 = blockIdx.x * 128, col0 = blockIdx.y * 128;

  const int oln  = ((lane & 3) - (lane >> 2)) & 3;
  const int srow = w * 32 + (lane >> 2);
  const u16* aS = A  + (size_t)(row0 + srow) * K + oln * 8;
  const u16* bS = Bt + (size_t)(col0 + srow) * K + oln * 8;
  const int stD = w * 1024;
  const int rdA = (wm * 64 + l15) * 32 + ((lhi + l15) & 3) * 8;
  const int rdB = (wn * 64 + l15) * 32 + ((lhi + l15) & 3) * 8;

  f32x4 acc[4][4] = {};

#define STAGE(KT, S)                                                            \
  {                                                                             \
    const size_t ko = (size_t)(KT) * 32;                                        \
    gload_lds16(aS + ko,          &sA[S][stD]);                                 \
    gload_lds16(aS + ko + 16 * K, &sA[S][stD + 512]);                           \
    gload_lds16(bS + ko,          &sB[S][stD]);                                 \
    gload_lds16(bS + ko + 16 * K, &sB[S][stD + 512]);                           \
  }
#define COMPUTE(S)                                                              \
  {                                                                             \
    bf16x8 af[4], bf[4];                                                        \
    _Pragma("unroll") for (int mi = 0; mi < 4; ++mi)                            \
      af[mi] = *(const bf16x8*)&sA[S][rdA + mi * 512];                          \
    _Pragma("unroll") for (int ni = 0; ni < 4; ++ni)                            \
      bf[ni] = *(const bf16x8*)&sB[S][rdB + ni * 512];                          \
    __builtin_amdgcn_s_setprio(1);                                              \
    _Pragma("unroll") for (int mi = 0; mi < 4; ++mi)                            \
      _Pragma("unroll") for (int ni = 0; ni < 4; ++ni)                          \
        acc[mi][ni] = __builtin_amdgcn_mfma_f32_16x16x32_bf16(af[mi], bf[ni],   \
                                                              acc[mi][ni], 0, 0, 0); \
    __builtin_amdgcn_s_setprio(0);                                              \
  }
#define WAITBAR4                                                                \
  asm volatile("s_waitcnt vmcnt(4)" ::: "memory");                              \
  __builtin_amdgcn_sched_barrier(0);                                            \
  __builtin_amdgcn_s_barrier();

  STAGE(0, 0);
  STAGE(1, 1);
  WAITBAR4;

  #pragma unroll 1
  for (int kt = 0; kt < 30; kt += 3) {
    STAGE(kt + 2, 2); COMPUTE(0); WAITBAR4;
    STAGE(kt + 3, 0); COMPUTE(1); WAITBAR4;
    STAGE(kt + 4, 1); COMPUTE(2); WAITBAR4;
  }
  COMPUTE(0);
  asm volatile("s_waitcnt vmcnt(0)" ::: "memory");
  __builtin_amdgcn_sched_barrier(0);
  __builtin_amdgcn_s_barrier();
  COMPUTE(1);
#undef STAGE
#undef COMPUTE
#undef WAITBAR4

  #pragma unroll
  for (int mt = 0; mt < 4; ++mt)
    #pragma unroll
    for (int nt = 0; nt < 4; ++nt)
      #pragma unroll
      for (int r = 0; r < 4; ++r) {
        const int rr = row0 + wm * 64 + mt * 16 + lhi * 4 + r;
        const int cc = col0 + wn * 64 + nt * 16 + l15;
        float v = acc[mt][nt][r];
        if constexpr (FUSE) {
          // C here is Qb (u16 [8192][1024]); Kc/Vc blocked-fragment tiles.
          if (cc < CDIM) {
            ((u16*)C)[(size_t)rr * CDIM + cc] = f32_to_bf16(v * 0.18033688011f);
          } else if (cc < 2 * CDIM) {
            const int d = cc - CDIM;
            const int h = d >> 6, dd = d & 63;
            const int bb = rr >> 11, t = rr & 2047;
            const size_t off = (size_t)(bb * 16 + h) * 131072 + (size_t)(t >> 5) * 2048
                + (size_t)(((t >> 4) & 1) * 2 + (dd >> 5)) * 512
                + ((dd >> 3) & 3) * 128 + (t & 15) * 8 + (dd & 7);
            Kc[off] = f32_to_bf16(v);
          } else {
            const int d = cc - 2 * CDIM;
            const int h = d >> 6, dv = d & 63;
            const int bb = rr >> 11, t = rr & 2047;
            const size_t off = (size_t)(bb * 16 + h) * 131072 + (size_t)(t >> 5) * 2048
                + (size_t)(dv >> 4) * 512 + ((t >> 3) & 3) * 128 + (dv & 15) * 8 + (t & 7);
            Vc[off] = f32_to_bf16(v);
          }
        } else {
          C[(size_t)rr * N + cc] = v;
        }
      }
}

// ---------------------------------------------------------------- flash attention
// Round-11 checkpoint (best): paired jobs (4k+w), block-shared LDS staging
// (double-buffered, __syncthreads), in-register P transpose, rowsum-via-MFMA,
// XCD clustering.  Q now read from compact Qb [8192][1024] (pre-scaled).
template <bool DOMASK>
__device__ __forceinline__ void attn_step(const bf16x8 (&qf)[2],
                                          const bf16x8 (&kf)[2][2],
                                          const bf16x8 (&vb)[4],
                                          const bf16x8 ones,
                                          f32x4 (&acc)[4], f32x4& acc1,
                                          int l15, int lhi, int kv0, int qg) {
  f32x4 st[2];
  #pragma unroll
  for (int t = 0; t < 2; ++t) {
    f32x4 z = {0.f, 0.f, 0.f, 0.f};
    z = __builtin_amdgcn_mfma_f32_16x16x32_bf16(kf[t][0], qf[0], z, 0, 0, 0);
    z = __builtin_amdgcn_mfma_f32_16x16x32_bf16(kf[t][1], qf[1], z, 0, 0, 0);
    st[t] = z;
  }
  #pragma unroll
  for (int t = 0; t < 2; ++t)
    #pragma unroll
    for (int r = 0; r < 4; ++r) {
      float sv = st[t][r];                       // Q pre-scaled: log2-domain score
      if (DOMASK) {
        const int kvg = kv0 + t * 16 + lhi * 4 + r;
        sv = (kvg > qg) ? -__builtin_inff() : sv;
      }
      st[t][r] = exp2f(sv);
    }
  unsigned c00, c01, c10, c11;
  asm("v_cvt_pk_bf16_f32 %0, %1, %2" : "=v"(c00) : "v"(st[0][0]), "v"(st[0][1]));
  asm("v_cvt_pk_bf16_f32 %0, %1, %2" : "=v"(c01) : "v"(st[0][2]), "v"(st[0][3]));
  asm("v_cvt_pk_bf16_f32 %0, %1, %2" : "=v"(c10) : "v"(st[1][0]), "v"(st[1][1]));
  asm("v_cvt_pk_bf16_f32 %0, %1, %2" : "=v"(c11) : "v"(st[1][2]), "v"(st[1][3]));
  asm("v_permlane32_swap_b32 %0, %1" : "+v"(c00), "+v"(c10));
  asm("v_permlane32_swap_b32 %0, %1" : "+v"(c01), "+v"(c11));
  asm("v_permlane16_swap_b32 %0, %1" : "+v"(c00), "+v"(c10));
  asm("v_permlane16_swap_b32 %0, %1" : "+v"(c01), "+v"(c11));
  uint32x4 pw; pw[0] = c00; pw[1] = c01; pw[2] = c10; pw[3] = c11;
  const bf16x8 pa = __builtin_bit_cast(bf16x8, pw);
  #pragma unroll
  for (int d = 0; d < 4; ++d)
    acc[d] = __builtin_amdgcn_mfma_f32_16x16x32_bf16(pa, vb[d], acc[d], 0, 0, 0);
  acc1 = __builtin_amdgcn_mfma_f32_16x16x32_bf16(pa, ones, acc1, 0, 0, 0);
}

__global__ __launch_bounds__(256, 4) void attn_kernel(const u16* __restrict__ Qb,
                                                      const u16* __restrict__ Kc,
                                                      const u16* __restrict__ Vc,
                                                      u16* __restrict__ Y) {
  __shared__ u16 Kl[2][2048];
  __shared__ u16 Vl[2][2048];
  const int tid = threadIdx.x, lane = tid & 63, wid = tid >> 6;
  const int l15 = lane & 15, lhi = lane >> 4;
  const int id = blockIdx.x;
  const int xcd = id & 7, k = (id >> 3) & 15, hi3 = id >> 7;
  const int bh = hi3 * 8 + xcd;
  const int b = bh >> 4, h = bh & 15;
  const int pa = k * 4 + wid;
  const int qA0 = pa * 16, qB0 = (127 - pa) * 16;
  const int nchA = pa / 2 + 1, nchB = (127 - pa) / 2 + 1;
  const int ncmax = (127 - k * 4) / 2 + 1;
  const u16* Qp  = Qb + (size_t)b * SEQ_T * CDIM + h * 64;
  const u16* KcC = Kc + (size_t)bh * 131072;
  const u16* VcC = Vc + (size_t)bh * 131072;

  u16x8 ou;
  #pragma unroll
  for (int j = 0; j < 8; ++j) ou[j] = 0x3F80;
  const bf16x8 ones = __builtin_bit_cast(bf16x8, ou);

  gload_lds16(KcC + wid * 512 + lane * 8, &Kl[0][wid * 512]);
  gload_lds16(VcC + wid * 512 + lane * 8, &Vl[0][wid * 512]);

  bf16x8 qfA[2], qfB[2];
  #pragma unroll
  for (int i = 0; i < 2; ++i) {
    qfA[i] = *(const bf16x8*)(Qp + (size_t)(qA0 + l15) * CDIM + i * 32 + lhi * 8);
    qfB[i] = *(const bf16x8*)(Qp + (size_t)(qB0 + l15) * CDIM + i * 32 + lhi * 8);
  }
  const int qgA = qA0 + l15, qgB = qB0 + l15;

  f32x4 accA[4] = {}, accB[4] = {};
  f32x4 acc1A = {}, acc1B = {};

  __syncthreads();

  int cbuf = 0;
  for (int ic = 0; ic < ncmax; ++ic) {
    if (ic + 1 < ncmax) {
      const u16* kg = KcC + (size_t)(ic + 1) * 2048 + wid * 512 + lane * 8;
      const u16* vg = VcC + (size_t)(ic + 1) * 2048 + wid * 512 + lane * 8;
      gload_lds16(kg, &Kl[cbuf ^ 1][wid * 512]);
      gload_lds16(vg, &Vl[cbuf ^ 1][wid * 512]);
    }
    const u16* kb = &Kl[cbuf][0];
    const u16* vp = &Vl[cbuf][0];
    bf16x8 kf[2][2], vb[4];
    #pragma unroll
    for (int t = 0; t < 2; ++t)
      #pragma unroll
      for (int i = 0; i < 2; ++i)
        kf[t][i] = *(const bf16x8*)(kb + (t * 2 + i) * 512 + lane * 8);
    #pragma unroll
    for (int d = 0; d < 4; ++d)
      vb[d] = *(const bf16x8*)(vp + d * 512 + lane * 8);

    const int kv0 = ic * 32;
    if (ic < nchB) {
      if (ic == nchB - 1)
        attn_step<true>(qfB, kf, vb, ones, accB, acc1B, l15, lhi, kv0, qgB);
      else
        attn_step<false>(qfB, kf, vb, ones, accB, acc1B, l15, lhi, kv0, qgB);
    }
    if (ic < nchA) {
      if (ic == nchA - 1)
        attn_step<true>(qfA, kf, vb, ones, accA, acc1A, l15, lhi, kv0, qgA);
      else
        attn_step<false>(qfA, kf, vb, ones, accA, acc1A, l15, lhi, kv0, qgA);
    }
    __syncthreads();
    cbuf ^= 1;
  }

  u16* Yp = Y + (size_t)b * SEQ_T * CDIM + h * 64;
  #pragma unroll
  for (int r = 0; r < 4; ++r) {
    const float ivA = 1.0f / acc1A[r];
    const float ivB = 1.0f / acc1B[r];
    #pragma unroll
    for (int d = 0; d < 4; ++d) {
      Yp[(size_t)(qA0 + lhi * 4 + r) * CDIM + d * 16 + l15] = f32_to_bf16(accA[d][r] * ivA);
      Yp[(size_t)(qB0 + lhi * 4 + r) * CDIM + d * 16 + l15] = f32_to_bf16(accB[d][r] * ivB);
    }
  }
}

// ---------------------------------------------------------------- launch
extern "C" void kernel_launch(void* const* d_in, const int* in_sizes, int n_in,
                              void* d_out, int out_size, void* d_ws, size_t ws_size,
                              hipStream_t stream) {
  const float* x      = (const float*)d_in[0];
  const float* w_qkv  = (const float*)d_in[1];
  const float* w_proj = (const float*)d_in[2];
  float* out = (float*)d_out;

  u16* Xb  = (u16*)d_ws;                                // 8192*1024 bf16
  u16* Wqt = Xb  + (size_t)MROWS * CDIM;                // 3072*1024
  u16* Wpt = Wqt + (size_t)QKVC * CDIM;                 // 1024*1024
  u16* Qb  = Wpt + (size_t)CDIM * CDIM;                 // 8192*1024 (Q, pre-scaled)
  u16* Kc  = Qb  + (size_t)MROWS * CDIM;                // 64*131072 blocked K
  u16* Vc  = Kc  + (size_t)64 * 131072;                 // 64*131072 blocked V
  u16* Yb  = Vc  + (size_t)64 * 131072;                 // 8192*1024

  // casts / transposes
  cast_bf16_kernel<<<(MROWS * CDIM / 4 + 255) / 256, 256, 0, stream>>>(x, Xb, MROWS * CDIM / 4);
  transpose_cast_kernel<<<dim3(QKVC / 32, CDIM / 32), dim3(32, 8), 0, stream>>>(w_qkv, Wqt, CDIM, QKVC);
  transpose_cast_kernel<<<dim3(CDIM / 32, CDIM / 32), dim3(32, 8), 0, stream>>>(w_proj, Wpt, CDIM, CDIM);

  // qkv projection with fused epilogue: Q -> Qb (scaled), K -> Kc, V -> Vc
  gemm_bt_kernel<true, u16><<<dim3(MROWS / 128, QKVC / 128), 256, 0, stream>>>(
      Xb, Wqt, Qb, Kc, Vc, QKVC, CDIM);

  // attention (round-11 checkpoint, Qb-compact)
  attn_kernel<<<1024, 256, 0, stream>>>(Qb, Kc, Vc, Yb);

  // out = y @ w_proj  (f32 out, 128x128 pipelined)
  gemm_bt_kernel<false, float><<<dim3(MROWS / 128, CDIM / 128), 256, 0, stream>>>(
      Yb, Wpt, out, nullptr, nullptr, CDIM, CDIM);
}

// Round 18
// 167.378 us; speedup vs baseline: 1.2210x; 1.0954x over previous
//
#include <hip/hip_runtime.h>

// Problem constants (B,T,C,H,Dh) = (4,2048,1024,16,64); M = B*T = 8192.
#define SEQ_T 2048
#define NBATCH 4
#define CDIM 1024
#define NHEAD 16
#define MROWS 8192      // NBATCH * SEQ_T
#define QKVC 3072       // 3*CDIM

typedef unsigned short u16;
typedef __bf16 bf16x8 __attribute__((ext_vector_type(8)));
typedef float f32x4 __attribute__((ext_vector_type(4)));
typedef unsigned short u16x8 __attribute__((ext_vector_type(8)));
typedef unsigned uint32x4 __attribute__((ext_vector_type(4)));

__device__ __forceinline__ u16 f32_to_bf16(float f) {
  union { float f; unsigned int u; } v; v.f = f;
  unsigned int u = v.u;
  unsigned int r = ((u >> 16) & 1u) + 0x7fffu;   // round-to-nearest-even
  return (u16)((u + r) >> 16);
}

__device__ __forceinline__ void gload_lds16(const u16* g, u16* l) {
  __builtin_amdgcn_global_load_lds(
      (const __attribute__((address_space(1))) void*)g,
      (__attribute__((address_space(3))) void*)l, 16, 0, 0);
}

// Blocked (MFMA-fragment-ordered) layout over a [R rows][K=1024] bf16 matrix:
// tile (row>>4, k>>5) is 1KB contiguous at index ((row>>4)*32 + (k>>5))*512;
// within, lane = (row&15) + (((k>>3)&3)<<4) holds 8 u16 at j = k&7.
// ds_read_b128 at base+lane*16B == exact 16x32 MFMA operand fragment.

// -------------------------------------------- cast f32 -> blocked bf16 (for Xb)
__global__ __launch_bounds__(256) void cast_block_kernel(const float* __restrict__ in,
                                                         u16* __restrict__ out) {
  const int i = blockIdx.x * 256 + threadIdx.x;   // over MROWS*CDIM/8
  const int kg = i & 127;                         // k-group of 8 (CDIM/8=128)
  const int row = i >> 7;
  const float4 v0 = ((const float4*)in)[i * 2];
  const float4 v1 = ((const float4*)in)[i * 2 + 1];
  union { u16 u[8]; bf16x8 b; } o;
  o.u[0] = f32_to_bf16(v0.x); o.u[1] = f32_to_bf16(v0.y);
  o.u[2] = f32_to_bf16(v0.z); o.u[3] = f32_to_bf16(v0.w);
  o.u[4] = f32_to_bf16(v1.x); o.u[5] = f32_to_bf16(v1.y);
  o.u[6] = f32_to_bf16(v1.z); o.u[7] = f32_to_bf16(v1.w);
  const int tile = (row >> 4) * 32 + (kg >> 2);
  const int lane = (row & 15) + ((kg & 3) << 4);
  *(bf16x8*)(out + (size_t)tile * 512 + lane * 8) = o.b;
}

// ------------------- transpose + cast w_qkv [1024][3072] -> blocked [3072][1024]
__global__ void transpose_cast_block_kernel(const float* __restrict__ in,
                                            u16* __restrict__ out) {
  __shared__ float tile[32][33];
  const int c0 = blockIdx.x * 32, r0 = blockIdx.y * 32;
  const int tx = threadIdx.x, ty = threadIdx.y;           // 32 x 8
  #pragma unroll
  for (int i = 0; i < 32; i += 8)
    tile[ty + i][tx] = in[(size_t)(r0 + ty + i) * QKVC + c0 + tx];
  __syncthreads();
  const int t = ty * 32 + tx;
  if (t < 128) {
    const int cc = t & 31, kgq = t >> 5;
    union { u16 u[8]; bf16x8 b; } o;
    #pragma unroll
    for (int j = 0; j < 8; ++j) o.u[j] = f32_to_bf16(tile[kgq * 8 + j][cc]);
    const int rowN = c0 + cc;
    const int tileI = (rowN >> 4) * 32 + (r0 >> 5);
    const int lane = (rowN & 15) + (kgq << 4);
    *(bf16x8*)(out + (size_t)tileI * 512 + lane * 8) = o.b;
  }
}

// ------------------------------------------- transpose + cast (linear, for Wpt)
__global__ void transpose_cast_kernel(const float* __restrict__ in, u16* __restrict__ out,
                                      int R, int Cc) {
  __shared__ float tile[32][33];
  int c0 = blockIdx.x * 32, r0 = blockIdx.y * 32;
  int tx = threadIdx.x, ty = threadIdx.y;   // 32 x 8
  #pragma unroll
  for (int i = 0; i < 32; i += 8)
    tile[ty + i][tx] = in[(size_t)(r0 + ty + i) * Cc + c0 + tx];
  __syncthreads();
  #pragma unroll
  for (int i = 0; i < 32; i += 8)
    out[(size_t)(c0 + ty + i) * R + r0 + tx] = f32_to_bf16(tile[tx][ty + i]);
}

// ---------------- GEMM1: 128x128 3-slot pipeline, BLOCKED inputs, fused epilogue
// Staging is wave-linear gload_lds (no swizzle needed); every ds_read_b128 is
// tile*512 + lane*16B -> conflict-free, zero addr VALU.  Epilogue: Q cols ->
// Qb (scaled, coalesced); K/V cols -> LDS scratch in Kc/Vc tile layout, then
// coalesced dwordx4 copy-out (replaces round-17's scalar global scatter).
__global__ __launch_bounds__(256, 3)
void gemm1_kernel(const u16* __restrict__ Ab, const u16* __restrict__ Bb,
                  u16* __restrict__ Qb, u16* __restrict__ Kc, u16* __restrict__ Vc) {
  __shared__ u16 lds[24576];            // 48KB: sA = lds+S*4096, sB = lds+12288+S*4096
  const int tid = threadIdx.x;
  const int lane = tid & 63, w = tid >> 6;
  const int wm = w >> 1, wn = w & 1;
  const int l15 = lane & 15, lhi = lane >> 4;
  const int row0 = blockIdx.x * 128, col0 = blockIdx.y * 128;
  const int rt0 = row0 >> 4, ct0 = col0 >> 4;

  const u16* aT = Ab + (size_t)(rt0 + w * 2) * 16384 + lane * 8;
  const u16* bT = Bb + (size_t)(ct0 + w * 2) * 16384 + lane * 8;

  f32x4 acc[4][4] = {};

#define SA(S) (lds + (S) * 4096)
#define SB(S) (lds + 12288 + (S) * 4096)
#define STAGE(KT, S)                                                            \
  {                                                                             \
    gload_lds16(aT + (size_t)(KT) * 512,         SA(S) + (w * 2) * 512);        \
    gload_lds16(aT + 16384 + (size_t)(KT) * 512, SA(S) + (w * 2 + 1) * 512);    \
    gload_lds16(bT + (size_t)(KT) * 512,         SB(S) + (w * 2) * 512);        \
    gload_lds16(bT + 16384 + (size_t)(KT) * 512, SB(S) + (w * 2 + 1) * 512);    \
  }
#define COMPUTE(S)                                                              \
  {                                                                             \
    bf16x8 af[4], bf[4];                                                        \
    _Pragma("unroll") for (int mi = 0; mi < 4; ++mi)                            \
      af[mi] = *(const bf16x8*)(SA(S) + (wm * 4 + mi) * 512 + lane * 8);        \
    _Pragma("unroll") for (int ni = 0; ni < 4; ++ni)                            \
      bf[ni] = *(const bf16x8*)(SB(S) + (wn * 4 + ni) * 512 + lane * 8);        \
    __builtin_amdgcn_s_setprio(1);                                              \
    _Pragma("unroll") for (int mi = 0; mi < 4; ++mi)                            \
      _Pragma("unroll") for (int ni = 0; ni < 4; ++ni)                          \
        acc[mi][ni] = __builtin_amdgcn_mfma_f32_16x16x32_bf16(af[mi], bf[ni],   \
                                                              acc[mi][ni], 0, 0, 0); \
    __builtin_amdgcn_s_setprio(0);                                              \
  }
#define WAITBAR4                                                                \
  asm volatile("s_waitcnt vmcnt(4)" ::: "memory");                              \
  __builtin_amdgcn_sched_barrier(0);                                            \
  __builtin_amdgcn_s_barrier();

  STAGE(0, 0);
  STAGE(1, 1);
  WAITBAR4;

  #pragma unroll 1
  for (int kt = 0; kt < 30; kt += 3) {
    STAGE(kt + 2, 2); COMPUTE(0); WAITBAR4;
    STAGE(kt + 3, 0); COMPUTE(1); WAITBAR4;
    STAGE(kt + 4, 1); COMPUTE(2); WAITBAR4;
  }
  COMPUTE(0);
  asm volatile("s_waitcnt vmcnt(0)" ::: "memory");
  __builtin_amdgcn_sched_barrier(0);
  __builtin_amdgcn_s_barrier();
  COMPUTE(1);
#undef STAGE
#undef COMPUTE
#undef WAITBAR4
#undef SA
#undef SB

  const int region = col0 >> 10;         // 0=Q, 1=K, 2=V (block-uniform)
  if (region == 0) {
    #pragma unroll
    for (int mt = 0; mt < 4; ++mt)
      #pragma unroll
      for (int nt = 0; nt < 4; ++nt)
        #pragma unroll
        for (int r = 0; r < 4; ++r) {
          const int rr = row0 + wm * 64 + mt * 16 + lhi * 4 + r;
          const int cc = col0 + wn * 64 + nt * 16 + l15;
          Qb[(size_t)rr * CDIM + cc] = f32_to_bf16(acc[mt][nt][r] * 0.18033688011f);
        }
  } else {
    __syncthreads();                     // all pipeline LDS reads done
    if (region == 1) {
      // K scratch: tile (hh=wn)*4 + kk, exact Kc within-tile layout
      #pragma unroll
      for (int mt = 0; mt < 4; ++mt)
        #pragma unroll
        for (int nt = 0; nt < 4; ++nt)
          #pragma unroll
          for (int r = 0; r < 4; ++r) {
            const int sidx = (wn * 4 + wm * 2 + (mt >> 1)) * 2048
                           + ((mt & 1) * 2 + (nt >> 1)) * 512
                           + ((nt & 1) * 2 + (l15 >> 3)) * 128
                           + (lhi * 4 + r) * 8 + (l15 & 7);
            lds[sidx] = f32_to_bf16(acc[mt][nt][r]);
          }
    } else {
      // V scratch: exact Vc within-tile layout
      #pragma unroll
      for (int mt = 0; mt < 4; ++mt)
        #pragma unroll
        for (int nt = 0; nt < 4; ++nt)
          #pragma unroll
          for (int r = 0; r < 4; ++r) {
            const int sidx = (wn * 4 + wm * 2 + (mt >> 1)) * 2048
                           + nt * 512
                           + ((mt & 1) * 2 + (lhi >> 1)) * 128
                           + l15 * 8 + (lhi & 1) * 4 + r;
            lds[sidx] = f32_to_bf16(acc[mt][nt][r]);
          }
    }
    __syncthreads();
    u16* dstB = (region == 1) ? Kc : Vc;
    const int bb = row0 >> 11;
    const int kv0b = (row0 & 2047) >> 5;
    const int hbase = (col0 & 1023) >> 6;
    #pragma unroll
    for (int hh = 0; hh < 2; ++hh) {
      u16* dst = dstB + (size_t)(bb * 16 + hbase + hh) * 131072 + (size_t)kv0b * 2048;
      const u16* src = lds + hh * 8192;
      #pragma unroll
      for (int c = 0; c < 4; ++c) {
        const int o = (c * 256 + tid) * 8;
        *(uint32x4*)(dst + o) = *(const uint32x4*)(src + o);
      }
    }
  }
}

// ------------------------------- GEMM2: round-9 128x128 pipelined (linear inputs)
__global__ __launch_bounds__(256, 3)
void gemm2_kernel(const u16* __restrict__ A, const u16* __restrict__ Bt,
                  float* __restrict__ C, int N, int K) {
  __shared__ u16 sA[3][4096];
  __shared__ u16 sB[3][4096];
  const int tid = threadIdx.x;
  const int lane = tid & 63, w = tid >> 6;
  const int wm = w >> 1, wn = w & 1;
  const int l15 = lane & 15, lhi = lane >> 4;
  const int row0 = blockIdx.x * 128, col0 = blockIdx.y * 128;

  const int oln  = ((lane & 3) - (lane >> 2)) & 3;
  const int srow = w * 32 + (lane >> 2);
  const u16* aS = A  + (size_t)(row0 + srow) * K + oln * 8;
  const u16* bS = Bt + (size_t)(col0 + srow) * K + oln * 8;
  const int stD = w * 1024;
  const int rdA = (wm * 64 + l15) * 32 + ((lhi + l15) & 3) * 8;
  const int rdB = (wn * 64 + l15) * 32 + ((lhi + l15) & 3) * 8;

  f32x4 acc[4][4] = {};

#define STAGE(KT, S)                                                            \
  {                                                                             \
    const size_t ko = (size_t)(KT) * 32;                                        \
    gload_lds16(aS + ko,          &sA[S][stD]);                                 \
    gload_lds16(aS + ko + 16 * K, &sA[S][stD + 512]);                           \
    gload_lds16(bS + ko,          &sB[S][stD]);                                 \
    gload_lds16(bS + ko + 16 * K, &sB[S][stD + 512]);                           \
  }
#define COMPUTE(S)                                                              \
  {                                                                             \
    bf16x8 af[4], bf[4];                                                        \
    _Pragma("unroll") for (int mi = 0; mi < 4; ++mi)                            \
      af[mi] = *(const bf16x8*)&sA[S][rdA + mi * 512];                          \
    _Pragma("unroll") for (int ni = 0; ni < 4; ++ni)                            \
      bf[ni] = *(const bf16x8*)&sB[S][rdB + ni * 512];                          \
    __builtin_amdgcn_s_setprio(1);                                              \
    _Pragma("unroll") for (int mi = 0; mi < 4; ++mi)                            \
      _Pragma("unroll") for (int ni = 0; ni < 4; ++ni)                          \
        acc[mi][ni] = __builtin_amdgcn_mfma_f32_16x16x32_bf16(af[mi], bf[ni],   \
                                                              acc[mi][ni], 0, 0, 0); \
    __builtin_amdgcn_s_setprio(0);                                              \
  }
#define WAITBAR4                                                                \
  asm volatile("s_waitcnt vmcnt(4)" ::: "memory");                              \
  __builtin_amdgcn_sched_barrier(0);                                            \
  __builtin_amdgcn_s_barrier();

  STAGE(0, 0);
  STAGE(1, 1);
  WAITBAR4;

  #pragma unroll 1
  for (int kt = 0; kt < 30; kt += 3) {
    STAGE(kt + 2, 2); COMPUTE(0); WAITBAR4;
    STAGE(kt + 3, 0); COMPUTE(1); WAITBAR4;
    STAGE(kt + 4, 1); COMPUTE(2); WAITBAR4;
  }
  COMPUTE(0);
  asm volatile("s_waitcnt vmcnt(0)" ::: "memory");
  __builtin_amdgcn_sched_barrier(0);
  __builtin_amdgcn_s_barrier();
  COMPUTE(1);
#undef STAGE
#undef COMPUTE
#undef WAITBAR4

  #pragma unroll
  for (int mt = 0; mt < 4; ++mt)
    #pragma unroll
    for (int nt = 0; nt < 4; ++nt)
      #pragma unroll
      for (int r = 0; r < 4; ++r) {
        const int rr = row0 + wm * 64 + mt * 16 + lhi * 4 + r;
        const int cc = col0 + wn * 64 + nt * 16 + l15;
        C[(size_t)rr * N + cc] = acc[mt][nt][r];
      }
}

// ---------------------------------------------------------------- flash attention
// Round-11 checkpoint: paired jobs (4k+w), block-shared LDS staging (dbuf,
// __syncthreads), in-register P transpose, rowsum-via-MFMA, XCD clustering.
template <bool DOMASK>
__device__ __forceinline__ void attn_step(const bf16x8 (&qf)[2],
                                          const bf16x8 (&kf)[2][2],
                                          const bf16x8 (&vb)[4],
                                          const bf16x8 ones,
                                          f32x4 (&acc)[4], f32x4& acc1,
                                          int l15, int lhi, int kv0, int qg) {
  f32x4 st[2];
  #pragma unroll
  for (int t = 0; t < 2; ++t) {
    f32x4 z = {0.f, 0.f, 0.f, 0.f};
    z = __builtin_amdgcn_mfma_f32_16x16x32_bf16(kf[t][0], qf[0], z, 0, 0, 0);
    z = __builtin_amdgcn_mfma_f32_16x16x32_bf16(kf[t][1], qf[1], z, 0, 0, 0);
    st[t] = z;
  }
  #pragma unroll
  for (int t = 0; t < 2; ++t)
    #pragma unroll
    for (int r = 0; r < 4; ++r) {
      float sv = st[t][r];                       // Q pre-scaled: log2-domain score
      if (DOMASK) {
        const int kvg = kv0 + t * 16 + lhi * 4 + r;
        sv = (kvg > qg) ? -__builtin_inff() : sv;
      }
      st[t][r] = exp2f(sv);
    }
  unsigned c00, c01, c10, c11;
  asm("v_cvt_pk_bf16_f32 %0, %1, %2" : "=v"(c00) : "v"(st[0][0]), "v"(st[0][1]));
  asm("v_cvt_pk_bf16_f32 %0, %1, %2" : "=v"(c01) : "v"(st[0][2]), "v"(st[0][3]));
  asm("v_cvt_pk_bf16_f32 %0, %1, %2" : "=v"(c10) : "v"(st[1][0]), "v"(st[1][1]));
  asm("v_cvt_pk_bf16_f32 %0, %1, %2" : "=v"(c11) : "v"(st[1][2]), "v"(st[1][3]));
  asm("v_permlane32_swap_b32 %0, %1" : "+v"(c00), "+v"(c10));
  asm("v_permlane32_swap_b32 %0, %1" : "+v"(c01), "+v"(c11));
  asm("v_permlane16_swap_b32 %0, %1" : "+v"(c00), "+v"(c10));
  asm("v_permlane16_swap_b32 %0, %1" : "+v"(c01), "+v"(c11));
  uint32x4 pw; pw[0] = c00; pw[1] = c01; pw[2] = c10; pw[3] = c11;
  const bf16x8 pa = __builtin_bit_cast(bf16x8, pw);
  #pragma unroll
  for (int d = 0; d < 4; ++d)
    acc[d] = __builtin_amdgcn_mfma_f32_16x16x32_bf16(pa, vb[d], acc[d], 0, 0, 0);
  acc1 = __builtin_amdgcn_mfma_f32_16x16x32_bf16(pa, ones, acc1, 0, 0, 0);
}

__global__ __launch_bounds__(256, 4) void attn_kernel(const u16* __restrict__ Qb,
                                                      const u16* __restrict__ Kc,
                                                      const u16* __restrict__ Vc,
                                                      u16* __restrict__ Y) {
  __shared__ u16 Kl[2][2048];
  __shared__ u16 Vl[2][2048];
  const int tid = threadIdx.x, lane = tid & 63, wid = tid >> 6;
  const int l15 = lane & 15, lhi = lane >> 4;
  const int id = blockIdx.x;
  const int xcd = id & 7, k = (id >> 3) & 15, hi3 = id >> 7;
  const int bh = hi3 * 8 + xcd;
  const int b = bh >> 4, h = bh & 15;
  const int pa = k * 4 + wid;
  const int qA0 = pa * 16, qB0 = (127 - pa) * 16;
  const int nchA = pa / 2 + 1, nchB = (127 - pa) / 2 + 1;
  const int ncmax = (127 - k * 4) / 2 + 1;
  const u16* Qp  = Qb + (size_t)b * SEQ_T * CDIM + h * 64;
  const u16* KcC = Kc + (size_t)bh * 131072;
  const u16* VcC = Vc + (size_t)bh * 131072;

  u16x8 ou;
  #pragma unroll
  for (int j = 0; j < 8; ++j) ou[j] = 0x3F80;
  const bf16x8 ones = __builtin_bit_cast(bf16x8, ou);

  gload_lds16(KcC + wid * 512 + lane * 8, &Kl[0][wid * 512]);
  gload_lds16(VcC + wid * 512 + lane * 8, &Vl[0][wid * 512]);

  bf16x8 qfA[2], qfB[2];
  #pragma unroll
  for (int i = 0; i < 2; ++i) {
    qfA[i] = *(const bf16x8*)(Qp + (size_t)(qA0 + l15) * CDIM + i * 32 + lhi * 8);
    qfB[i] = *(const bf16x8*)(Qp + (size_t)(qB0 + l15) * CDIM + i * 32 + lhi * 8);
  }
  const int qgA = qA0 + l15, qgB = qB0 + l15;

  f32x4 accA[4] = {}, accB[4] = {};
  f32x4 acc1A = {}, acc1B = {};

  __syncthreads();

  int cbuf = 0;
  for (int ic = 0; ic < ncmax; ++ic) {
    if (ic + 1 < ncmax) {
      const u16* kg = KcC + (size_t)(ic + 1) * 2048 + wid * 512 + lane * 8;
      const u16* vg = VcC + (size_t)(ic + 1) * 2048 + wid * 512 + lane * 8;
      gload_lds16(kg, &Kl[cbuf ^ 1][wid * 512]);
      gload_lds16(vg, &Vl[cbuf ^ 1][wid * 512]);
    }
    const u16* kb = &Kl[cbuf][0];
    const u16* vp = &Vl[cbuf][0];
    bf16x8 kf[2][2], vb[4];
    #pragma unroll
    for (int t = 0; t < 2; ++t)
      #pragma unroll
      for (int i = 0; i < 2; ++i)
        kf[t][i] = *(const bf16x8*)(kb + (t * 2 + i) * 512 + lane * 8);
    #pragma unroll
    for (int d = 0; d < 4; ++d)
      vb[d] = *(const bf16x8*)(vp + d * 512 + lane * 8);

    const int kv0 = ic * 32;
    if (ic < nchB) {
      if (ic == nchB - 1)
        attn_step<true>(qfB, kf, vb, ones, accB, acc1B, l15, lhi, kv0, qgB);
      else
        attn_step<false>(qfB, kf, vb, ones, accB, acc1B, l15, lhi, kv0, qgB);
    }
    if (ic < nchA) {
      if (ic == nchA - 1)
        attn_step<true>(qfA, kf, vb, ones, accA, acc1A, l15, lhi, kv0, qgA);
      else
        attn_step<false>(qfA, kf, vb, ones, accA, acc1A, l15, lhi, kv0, qgA);
    }
    __syncthreads();
    cbuf ^= 1;
  }

  u16* Yp = Y + (size_t)b * SEQ_T * CDIM + h * 64;
  #pragma unroll
  for (int r = 0; r < 4; ++r) {
    const float ivA = 1.0f / acc1A[r];
    const float ivB = 1.0f / acc1B[r];
    #pragma unroll
    for (int d = 0; d < 4; ++d) {
      Yp[(size_t)(qA0 + lhi * 4 + r) * CDIM + d * 16 + l15] = f32_to_bf16(accA[d][r] * ivA);
      Yp[(size_t)(qB0 + lhi * 4 + r) * CDIM + d * 16 + l15] = f32_to_bf16(accB[d][r] * ivB);
    }
  }
}

// ---------------------------------------------------------------- launch
extern "C" void kernel_launch(void* const* d_in, const int* in_sizes, int n_in,
                              void* d_out, int out_size, void* d_ws, size_t ws_size,
                              hipStream_t stream) {
  const float* x      = (const float*)d_in[0];
  const float* w_qkv  = (const float*)d_in[1];
  const float* w_proj = (const float*)d_in[2];
  float* out = (float*)d_out;

  u16* Xb  = (u16*)d_ws;                                // blocked x
  u16* Wqt = Xb  + (size_t)MROWS * CDIM;                // blocked w_qkv^T
  u16* Wpt = Wqt + (size_t)QKVC * CDIM;                 // linear  w_proj^T
  u16* Qb  = Wpt + (size_t)CDIM * CDIM;                 // 8192*1024 (Q, pre-scaled)
  u16* Kc  = Qb  + (size_t)MROWS * CDIM;                // 64*131072 blocked K
  u16* Vc  = Kc  + (size_t)64 * 131072;                 // 64*131072 blocked V
  u16* Yb  = Vc  + (size_t)64 * 131072;                 // 8192*1024 linear

  // casts / transposes
  cast_block_kernel<<<MROWS * CDIM / 8 / 256, 256, 0, stream>>>(x, Xb);
  transpose_cast_block_kernel<<<dim3(QKVC / 32, CDIM / 32), dim3(32, 8), 0, stream>>>(w_qkv, Wqt);
  transpose_cast_kernel<<<dim3(CDIM / 32, CDIM / 32), dim3(32, 8), 0, stream>>>(w_proj, Wpt, CDIM, CDIM);

  // qkv projection: blocked inputs, fused epilogue (Q->Qb scaled, K->Kc, V->Vc)
  gemm1_kernel<<<dim3(MROWS / 128, QKVC / 128), 256, 0, stream>>>(Xb, Wqt, Qb, Kc, Vc);

  // attention (round-11 checkpoint)
  attn_kernel<<<1024, 256, 0, stream>>>(Qb, Kc, Vc, Yb);

  // out = y @ w_proj  (f32 out)
  gemm2_kernel<<<dim3(MROWS / 128, CDIM / 128), 256, 0, stream>>>(Yb, Wpt, out, CDIM, CDIM);
}

// Round 19
// 156.088 us; speedup vs baseline: 1.3093x; 1.0723x over previous
//
#include <hip/hip_runtime.h>

// Problem constants (B,T,C,H,Dh) = (4,2048,1024,16,64); M = B*T = 8192.
#define SEQ_T 2048
#define NBATCH 4
#define CDIM 1024
#define NHEAD 16
#define MROWS 8192      // NBATCH * SEQ_T
#define QKVC 3072       // 3*CDIM

typedef unsigned short u16;
typedef __bf16 bf16x8 __attribute__((ext_vector_type(8)));
typedef float f32x4 __attribute__((ext_vector_type(4)));
typedef unsigned short u16x8 __attribute__((ext_vector_type(8)));
typedef unsigned uint32x4 __attribute__((ext_vector_type(4)));

__device__ __forceinline__ u16 f32_to_bf16(float f) {
  union { float f; unsigned int u; } v; v.f = f;
  unsigned int u = v.u;
  unsigned int r = ((u >> 16) & 1u) + 0x7fffu;   // round-to-nearest-even
  return (u16)((u + r) >> 16);
}

__device__ __forceinline__ void gload_lds16(const u16* g, u16* l) {
  __builtin_amdgcn_global_load_lds(
      (const __attribute__((address_space(1))) void*)g,
      (__attribute__((address_space(3))) void*)l, 16, 0, 0);
}

// Blocked (MFMA-fragment-ordered) layout over a [R rows][K=1024] bf16 matrix:
// tile (row>>4, k>>5) is 1KB contiguous at index ((row>>4)*32 + (k>>5))*512;
// within, lane = (row&15) + (((k>>3)&3)<<4) holds 8 u16 at j = k&7.

// -------------------------------------------- cast f32 -> blocked bf16 (for Xb)
__global__ __launch_bounds__(256) void cast_block_kernel(const float* __restrict__ in,
                                                         u16* __restrict__ out) {
  const int i = blockIdx.x * 256 + threadIdx.x;   // over MROWS*CDIM/8
  const int kg = i & 127;                         // k-group of 8 (CDIM/8=128)
  const int row = i >> 7;
  const float4 v0 = ((const float4*)in)[i * 2];
  const float4 v1 = ((const float4*)in)[i * 2 + 1];
  union { u16 u[8]; bf16x8 b; } o;
  o.u[0] = f32_to_bf16(v0.x); o.u[1] = f32_to_bf16(v0.y);
  o.u[2] = f32_to_bf16(v0.z); o.u[3] = f32_to_bf16(v0.w);
  o.u[4] = f32_to_bf16(v1.x); o.u[5] = f32_to_bf16(v1.y);
  o.u[6] = f32_to_bf16(v1.z); o.u[7] = f32_to_bf16(v1.w);
  const int tile = (row >> 4) * 32 + (kg >> 2);
  const int lane = (row & 15) + ((kg & 3) << 4);
  *(bf16x8*)(out + (size_t)tile * 512 + lane * 8) = o.b;
}

// --------- transpose + cast W [1024][Cc] -> blocked [Cc rows][1024 k]
__global__ void transpose_cast_block_kernel(const float* __restrict__ in,
                                            u16* __restrict__ out, int Cc) {
  __shared__ float tile[32][33];
  const int c0 = blockIdx.x * 32, r0 = blockIdx.y * 32;
  const int tx = threadIdx.x, ty = threadIdx.y;           // 32 x 8
  #pragma unroll
  for (int i = 0; i < 32; i += 8)
    tile[ty + i][tx] = in[(size_t)(r0 + ty + i) * Cc + c0 + tx];
  __syncthreads();
  const int t = ty * 32 + tx;
  if (t < 128) {
    const int cc = t & 31, kgq = t >> 5;
    union { u16 u[8]; bf16x8 b; } o;
    #pragma unroll
    for (int j = 0; j < 8; ++j) o.u[j] = f32_to_bf16(tile[kgq * 8 + j][cc]);
    const int rowN = c0 + cc;
    const int tileI = (rowN >> 4) * 32 + (r0 >> 5);
    const int lane = (rowN & 15) + (kgq << 4);
    *(bf16x8*)(out + (size_t)tileI * 512 + lane * 8) = o.b;
  }
}

// ---------------- GEMM1: 128x128 3-slot pipeline, BLOCKED inputs, fused epilogue
__global__ __launch_bounds__(256, 3)
void gemm1_kernel(const u16* __restrict__ Ab, const u16* __restrict__ Bb,
                  u16* __restrict__ Qb, u16* __restrict__ Kc, u16* __restrict__ Vc) {
  __shared__ u16 lds[24576];            // 48KB
  const int tid = threadIdx.x;
  const int lane = tid & 63, w = tid >> 6;
  const int wm = w >> 1, wn = w & 1;
  const int l15 = lane & 15, lhi = lane >> 4;
  const int row0 = blockIdx.x * 128, col0 = blockIdx.y * 128;
  const int rt0 = row0 >> 4, ct0 = col0 >> 4;

  const u16* aT = Ab + (size_t)(rt0 + w * 2) * 16384 + lane * 8;
  const u16* bT = Bb + (size_t)(ct0 + w * 2) * 16384 + lane * 8;

  f32x4 acc[4][4] = {};

#define SA(S) (lds + (S) * 4096)
#define SB(S) (lds + 12288 + (S) * 4096)
#define STAGE(KT, S)                                                            \
  {                                                                             \
    gload_lds16(aT + (size_t)(KT) * 512,         SA(S) + (w * 2) * 512);        \
    gload_lds16(aT + 16384 + (size_t)(KT) * 512, SA(S) + (w * 2 + 1) * 512);    \
    gload_lds16(bT + (size_t)(KT) * 512,         SB(S) + (w * 2) * 512);        \
    gload_lds16(bT + 16384 + (size_t)(KT) * 512, SB(S) + (w * 2 + 1) * 512);    \
  }
#define COMPUTE(S)                                                              \
  {                                                                             \
    bf16x8 af[4], bf[4];                                                        \
    _Pragma("unroll") for (int mi = 0; mi < 4; ++mi)                            \
      af[mi] = *(const bf16x8*)(SA(S) + (wm * 4 + mi) * 512 + lane * 8);        \
    _Pragma("unroll") for (int ni = 0; ni < 4; ++ni)                            \
      bf[ni] = *(const bf16x8*)(SB(S) + (wn * 4 + ni) * 512 + lane * 8);        \
    __builtin_amdgcn_s_setprio(1);                                              \
    _Pragma("unroll") for (int mi = 0; mi < 4; ++mi)                            \
      _Pragma("unroll") for (int ni = 0; ni < 4; ++ni)                          \
        acc[mi][ni] = __builtin_amdgcn_mfma_f32_16x16x32_bf16(af[mi], bf[ni],   \
                                                              acc[mi][ni], 0, 0, 0); \
    __builtin_amdgcn_s_setprio(0);                                              \
  }
#define WAITBAR4                                                                \
  asm volatile("s_waitcnt vmcnt(4)" ::: "memory");                              \
  __builtin_amdgcn_sched_barrier(0);                                            \
  __builtin_amdgcn_s_barrier();

  STAGE(0, 0);
  STAGE(1, 1);
  WAITBAR4;

  #pragma unroll 1
  for (int kt = 0; kt < 30; kt += 3) {
    STAGE(kt + 2, 2); COMPUTE(0); WAITBAR4;
    STAGE(kt + 3, 0); COMPUTE(1); WAITBAR4;
    STAGE(kt + 4, 1); COMPUTE(2); WAITBAR4;
  }
  COMPUTE(0);
  asm volatile("s_waitcnt vmcnt(0)" ::: "memory");
  __builtin_amdgcn_sched_barrier(0);
  __builtin_amdgcn_s_barrier();
  COMPUTE(1);
#undef STAGE
#undef COMPUTE
#undef WAITBAR4
#undef SA
#undef SB

  const int region = col0 >> 10;         // 0=Q, 1=K, 2=V (block-uniform)
  if (region == 0) {
    #pragma unroll
    for (int mt = 0; mt < 4; ++mt)
      #pragma unroll
      for (int nt = 0; nt < 4; ++nt)
        #pragma unroll
        for (int r = 0; r < 4; ++r) {
          const int rr = row0 + wm * 64 + mt * 16 + lhi * 4 + r;
          const int cc = col0 + wn * 64 + nt * 16 + l15;
          Qb[(size_t)rr * CDIM + cc] = f32_to_bf16(acc[mt][nt][r] * 0.18033688011f);
        }
  } else {
    __syncthreads();
    if (region == 1) {
      #pragma unroll
      for (int mt = 0; mt < 4; ++mt)
        #pragma unroll
        for (int nt = 0; nt < 4; ++nt)
          #pragma unroll
          for (int r = 0; r < 4; ++r) {
            const int sidx = (wn * 4 + wm * 2 + (mt >> 1)) * 2048
                           + ((mt & 1) * 2 + (nt >> 1)) * 512
                           + ((nt & 1) * 2 + (l15 >> 3)) * 128
                           + (lhi * 4 + r) * 8 + (l15 & 7);
            lds[sidx] = f32_to_bf16(acc[mt][nt][r]);
          }
    } else {
      #pragma unroll
      for (int mt = 0; mt < 4; ++mt)
        #pragma unroll
        for (int nt = 0; nt < 4; ++nt)
          #pragma unroll
          for (int r = 0; r < 4; ++r) {
            const int sidx = (wn * 4 + wm * 2 + (mt >> 1)) * 2048
                           + nt * 512
                           + ((mt & 1) * 2 + (lhi >> 1)) * 128
                           + l15 * 8 + (lhi & 1) * 4 + r;
            lds[sidx] = f32_to_bf16(acc[mt][nt][r]);
          }
    }
    __syncthreads();
    u16* dstB = (region == 1) ? Kc : Vc;
    const int bb = row0 >> 11;
    const int kv0b = (row0 & 2047) >> 5;
    const int hbase = (col0 & 1023) >> 6;
    #pragma unroll
    for (int hh = 0; hh < 2; ++hh) {
      u16* dst = dstB + (size_t)(bb * 16 + hbase + hh) * 131072 + (size_t)kv0b * 2048;
      const u16* src = lds + hh * 8192;
      #pragma unroll
      for (int c = 0; c < 4; ++c) {
        const int o = (c * 256 + tid) * 8;
        *(uint32x4*)(dst + o) = *(const uint32x4*)(src + o);
      }
    }
  }
}

// ---------------- GEMM2: 128x128 3-slot pipeline, BLOCKED inputs, f32 output
__global__ __launch_bounds__(256, 3)
void gemm2_kernel(const u16* __restrict__ Ab, const u16* __restrict__ Bb,
                  float* __restrict__ C) {
  __shared__ u16 lds[24576];
  const int tid = threadIdx.x;
  const int lane = tid & 63, w = tid >> 6;
  const int wm = w >> 1, wn = w & 1;
  const int l15 = lane & 15, lhi = lane >> 4;
  const int row0 = blockIdx.x * 128, col0 = blockIdx.y * 128;
  const int rt0 = row0 >> 4, ct0 = col0 >> 4;

  const u16* aT = Ab + (size_t)(rt0 + w * 2) * 16384 + lane * 8;
  const u16* bT = Bb + (size_t)(ct0 + w * 2) * 16384 + lane * 8;

  f32x4 acc[4][4] = {};

#define SA(S) (lds + (S) * 4096)
#define SB(S) (lds + 12288 + (S) * 4096)
#define STAGE(KT, S)                                                            \
  {                                                                             \
    gload_lds16(aT + (size_t)(KT) * 512,         SA(S) + (w * 2) * 512);        \
    gload_lds16(aT + 16384 + (size_t)(KT) * 512, SA(S) + (w * 2 + 1) * 512);    \
    gload_lds16(bT + (size_t)(KT) * 512,         SB(S) + (w * 2) * 512);        \
    gload_lds16(bT + 16384 + (size_t)(KT) * 512, SB(S) + (w * 2 + 1) * 512);    \
  }
#define COMPUTE(S)                                                              \
  {                                                                             \
    bf16x8 af[4], bf[4];                                                        \
    _Pragma("unroll") for (int mi = 0; mi < 4; ++mi)                            \
      af[mi] = *(const bf16x8*)(SA(S) + (wm * 4 + mi) * 512 + lane * 8);        \
    _Pragma("unroll") for (int ni = 0; ni < 4; ++ni)                            \
      bf[ni] = *(const bf16x8*)(SB(S) + (wn * 4 + ni) * 512 + lane * 8);        \
    __builtin_amdgcn_s_setprio(1);                                              \
    _Pragma("unroll") for (int mi = 0; mi < 4; ++mi)                            \
      _Pragma("unroll") for (int ni = 0; ni < 4; ++ni)                          \
        acc[mi][ni] = __builtin_amdgcn_mfma_f32_16x16x32_bf16(af[mi], bf[ni],   \
                                                              acc[mi][ni], 0, 0, 0); \
    __builtin_amdgcn_s_setprio(0);                                              \
  }
#define WAITBAR4                                                                \
  asm volatile("s_waitcnt vmcnt(4)" ::: "memory");                              \
  __builtin_amdgcn_sched_barrier(0);                                            \
  __builtin_amdgcn_s_barrier();

  STAGE(0, 0);
  STAGE(1, 1);
  WAITBAR4;

  #pragma unroll 1
  for (int kt = 0; kt < 30; kt += 3) {
    STAGE(kt + 2, 2); COMPUTE(0); WAITBAR4;
    STAGE(kt + 3, 0); COMPUTE(1); WAITBAR4;
    STAGE(kt + 4, 1); COMPUTE(2); WAITBAR4;
  }
  COMPUTE(0);
  asm volatile("s_waitcnt vmcnt(0)" ::: "memory");
  __builtin_amdgcn_sched_barrier(0);
  __builtin_amdgcn_s_barrier();
  COMPUTE(1);
#undef STAGE
#undef COMPUTE
#undef WAITBAR4
#undef SA
#undef SB

  #pragma unroll
  for (int mt = 0; mt < 4; ++mt)
    #pragma unroll
    for (int nt = 0; nt < 4; ++nt)
      #pragma unroll
      for (int r = 0; r < 4; ++r) {
        const int rr = row0 + wm * 64 + mt * 16 + lhi * 4 + r;
        const int cc = col0 + wn * 64 + nt * 16 + l15;
        C[(size_t)rr * CDIM + cc] = acc[mt][nt][r];
      }
}

// ---------------------------------------------------------------- flash attention
// Round-19: KVBLK=64.  Two 32-kv halves per barrier pair (halves the per-
// iteration fixed cost: barriers, prefetch issue, lockstep).  Fragments are
// re-read from LDS per half -> register footprint unchanged.  Epilogue writes
// Yb in BLOCKED layout (feeds gemm2's conflict-free blocked path).
template <bool DOMASK>
__device__ __forceinline__ void attn_step(const bf16x8 (&qf)[2],
                                          const bf16x8 (&kf)[2][2],
                                          const bf16x8 (&vb)[4],
                                          const bf16x8 ones,
                                          f32x4 (&acc)[4], f32x4& acc1,
                                          int l15, int lhi, int kv0, int qg) {
  f32x4 st[2];
  #pragma unroll
  for (int t = 0; t < 2; ++t) {
    f32x4 z = {0.f, 0.f, 0.f, 0.f};
    z = __builtin_amdgcn_mfma_f32_16x16x32_bf16(kf[t][0], qf[0], z, 0, 0, 0);
    z = __builtin_amdgcn_mfma_f32_16x16x32_bf16(kf[t][1], qf[1], z, 0, 0, 0);
    st[t] = z;
  }
  #pragma unroll
  for (int t = 0; t < 2; ++t)
    #pragma unroll
    for (int r = 0; r < 4; ++r) {
      float sv = st[t][r];                       // Q pre-scaled: log2-domain score
      if (DOMASK) {
        const int kvg = kv0 + t * 16 + lhi * 4 + r;
        sv = (kvg > qg) ? -__builtin_inff() : sv;
      }
      st[t][r] = exp2f(sv);
    }
  unsigned c00, c01, c10, c11;
  asm("v_cvt_pk_bf16_f32 %0, %1, %2" : "=v"(c00) : "v"(st[0][0]), "v"(st[0][1]));
  asm("v_cvt_pk_bf16_f32 %0, %1, %2" : "=v"(c01) : "v"(st[0][2]), "v"(st[0][3]));
  asm("v_cvt_pk_bf16_f32 %0, %1, %2" : "=v"(c10) : "v"(st[1][0]), "v"(st[1][1]));
  asm("v_cvt_pk_bf16_f32 %0, %1, %2" : "=v"(c11) : "v"(st[1][2]), "v"(st[1][3]));
  asm("v_permlane32_swap_b32 %0, %1" : "+v"(c00), "+v"(c10));
  asm("v_permlane32_swap_b32 %0, %1" : "+v"(c01), "+v"(c11));
  asm("v_permlane16_swap_b32 %0, %1" : "+v"(c00), "+v"(c10));
  asm("v_permlane16_swap_b32 %0, %1" : "+v"(c01), "+v"(c11));
  uint32x4 pw; pw[0] = c00; pw[1] = c01; pw[2] = c10; pw[3] = c11;
  const bf16x8 pa = __builtin_bit_cast(bf16x8, pw);
  #pragma unroll
  for (int d = 0; d < 4; ++d)
    acc[d] = __builtin_amdgcn_mfma_f32_16x16x32_bf16(pa, vb[d], acc[d], 0, 0, 0);
  acc1 = __builtin_amdgcn_mfma_f32_16x16x32_bf16(pa, ones, acc1, 0, 0, 0);
}

__global__ __launch_bounds__(256, 4) void attn_kernel(const u16* __restrict__ Qb,
                                                      const u16* __restrict__ Kc,
                                                      const u16* __restrict__ Vc,
                                                      u16* __restrict__ Yb) {
  __shared__ u16 Kl[2][4096];     // [buf][2 chunks x 2048] = 8KB each
  __shared__ u16 Vl[2][4096];
  const int tid = threadIdx.x, lane = tid & 63, wid = tid >> 6;
  const int l15 = lane & 15, lhi = lane >> 4;
  const int id = blockIdx.x;
  const int xcd = id & 7, k = (id >> 3) & 15, hi3 = id >> 7;
  const int bh = hi3 * 8 + xcd;
  const int b = bh >> 4, h = bh & 15;
  const int pa = k * 4 + wid;
  const int qA0 = pa * 16, qB0 = (127 - pa) * 16;
  const int nchA = pa / 2 + 1, nchB = (127 - pa) / 2 + 1;
  const int nc2max = 32 - k;                     // = ncmax/2 (ncmax = 64-2k, even)
  const u16* Qp  = Qb + (size_t)b * SEQ_T * CDIM + h * 64;
  const u16* KcC = Kc + (size_t)bh * 131072;
  const u16* VcC = Vc + (size_t)bh * 131072;

  u16x8 ou;
  #pragma unroll
  for (int j = 0; j < 8; ++j) ou[j] = 0x3F80;
  const bf16x8 ones = __builtin_bit_cast(bf16x8, ou);

  // stage chunk pair 0 (each wave: 2KB of K + 2KB of V)
  gload_lds16(KcC + wid * 512 + lane * 8,        &Kl[0][wid * 512]);
  gload_lds16(KcC + 2048 + wid * 512 + lane * 8, &Kl[0][2048 + wid * 512]);
  gload_lds16(VcC + wid * 512 + lane * 8,        &Vl[0][wid * 512]);
  gload_lds16(VcC + 2048 + wid * 512 + lane * 8, &Vl[0][2048 + wid * 512]);

  bf16x8 qfA[2], qfB[2];
  #pragma unroll
  for (int i = 0; i < 2; ++i) {
    qfA[i] = *(const bf16x8*)(Qp + (size_t)(qA0 + l15) * CDIM + i * 32 + lhi * 8);
    qfB[i] = *(const bf16x8*)(Qp + (size_t)(qB0 + l15) * CDIM + i * 32 + lhi * 8);
  }
  const int qgA = qA0 + l15, qgB = qB0 + l15;

  f32x4 accA[4] = {}, accB[4] = {};
  f32x4 acc1A = {}, acc1B = {};

  __syncthreads();

  int cbuf = 0;
  for (int ic2 = 0; ic2 < nc2max; ++ic2) {
    if (ic2 + 1 < nc2max) {
      const u16* kg = KcC + (size_t)(ic2 + 1) * 4096 + wid * 512 + lane * 8;
      const u16* vg = VcC + (size_t)(ic2 + 1) * 4096 + wid * 512 + lane * 8;
      gload_lds16(kg,        &Kl[cbuf ^ 1][wid * 512]);
      gload_lds16(kg + 2048, &Kl[cbuf ^ 1][2048 + wid * 512]);
      gload_lds16(vg,        &Vl[cbuf ^ 1][wid * 512]);
      gload_lds16(vg + 2048, &Vl[cbuf ^ 1][2048 + wid * 512]);
    }
    #pragma unroll
    for (int h2 = 0; h2 < 2; ++h2) {
      const int c = ic2 * 2 + h2;
      const u16* kb = &Kl[cbuf][h2 * 2048];
      const u16* vp = &Vl[cbuf][h2 * 2048];
      bf16x8 kf[2][2], vb[4];
      #pragma unroll
      for (int t = 0; t < 2; ++t)
        #pragma unroll
        for (int i = 0; i < 2; ++i)
          kf[t][i] = *(const bf16x8*)(kb + (t * 2 + i) * 512 + lane * 8);
      #pragma unroll
      for (int d = 0; d < 4; ++d)
        vb[d] = *(const bf16x8*)(vp + d * 512 + lane * 8);

      const int kv0 = c * 32;
      if (c < nchB) {
        if (c == nchB - 1)
          attn_step<true>(qfB, kf, vb, ones, accB, acc1B, l15, lhi, kv0, qgB);
        else
          attn_step<false>(qfB, kf, vb, ones, accB, acc1B, l15, lhi, kv0, qgB);
      }
      if (c < nchA) {
        if (c == nchA - 1)
          attn_step<true>(qfA, kf, vb, ones, accA, acc1A, l15, lhi, kv0, qgA);
        else
          attn_step<false>(qfA, kf, vb, ones, accA, acc1A, l15, lhi, kv0, qgA);
      }
    }
    __syncthreads();
    cbuf ^= 1;
  }

  // epilogue: rowsum in acc1[r]; write Yb in BLOCKED layout
  // row rr = b*2048 + q; k-col = h*64 + d*16 + l15.
  // off = ((rr>>4)*32 + h*2 + (d>>1))*512 + ((rr&15) + ((d*2+(l15>>3))&3)*16)*8 + (l15&7)
  #pragma unroll
  for (int r = 0; r < 4; ++r) {
    const float ivA = 1.0f / acc1A[r];
    const float ivB = 1.0f / acc1B[r];
    const int rl = lhi * 4 + r;                  // rr & 15
    #pragma unroll
    for (int d = 0; d < 4; ++d) {
      const int lofs = (rl + (((d * 2 + (l15 >> 3)) & 3) << 4)) * 8 + (l15 & 7);
      Yb[((size_t)(b * 128 + pa)        * 32 + h * 2 + (d >> 1)) * 512 + lofs] =
          f32_to_bf16(accA[d][r] * ivA);
      Yb[((size_t)(b * 128 + (127 - pa)) * 32 + h * 2 + (d >> 1)) * 512 + lofs] =
          f32_to_bf16(accB[d][r] * ivB);
    }
  }
}

// ---------------------------------------------------------------- launch
extern "C" void kernel_launch(void* const* d_in, const int* in_sizes, int n_in,
                              void* d_out, int out_size, void* d_ws, size_t ws_size,
                              hipStream_t stream) {
  const float* x      = (const float*)d_in[0];
  const float* w_qkv  = (const float*)d_in[1];
  const float* w_proj = (const float*)d_in[2];
  float* out = (float*)d_out;

  u16* Xb  = (u16*)d_ws;                                // blocked x
  u16* Wqt = Xb  + (size_t)MROWS * CDIM;                // blocked w_qkv^T
  u16* Wpt = Wqt + (size_t)QKVC * CDIM;                 // blocked w_proj^T
  u16* Qb  = Wpt + (size_t)CDIM * CDIM;                 // 8192*1024 (Q, pre-scaled)
  u16* Kc  = Qb  + (size_t)MROWS * CDIM;                // 64*131072 blocked K
  u16* Vc  = Kc  + (size_t)64 * 131072;                 // 64*131072 blocked V
  u16* Yb  = Vc  + (size_t)64 * 131072;                 // 8192*1024 blocked

  // casts / transposes (all blocked)
  cast_block_kernel<<<MROWS * CDIM / 8 / 256, 256, 0, stream>>>(x, Xb);
  transpose_cast_block_kernel<<<dim3(QKVC / 32, CDIM / 32), dim3(32, 8), 0, stream>>>(w_qkv, Wqt, QKVC);
  transpose_cast_block_kernel<<<dim3(CDIM / 32, CDIM / 32), dim3(32, 8), 0, stream>>>(w_proj, Wpt, CDIM);

  // qkv projection: blocked inputs, fused epilogue (Q->Qb scaled, K->Kc, V->Vc)
  gemm1_kernel<<<dim3(MROWS / 128, QKVC / 128), 256, 0, stream>>>(Xb, Wqt, Qb, Kc, Vc);

  // attention (KVBLK=64, blocked Yb write)
  attn_kernel<<<1024, 256, 0, stream>>>(Qb, Kc, Vc, Yb);

  // out = y @ w_proj  (blocked inputs, f32 out)
  gemm2_kernel<<<dim3(MROWS / 128, CDIM / 128), 256, 0, stream>>>(Yb, Wpt, out);
}